// Round 1
// baseline (791.070 us; speedup 1.0000x reference)
//
#include <hip/hip_runtime.h>
#include <math.h>

// B=8, T=2048, D=128, NH=4, HD=32. BT = 16384 rows. All f32.
// Pipeline:
//  1. impact = tanh(LN(trade @ ei_w.T + ei_b)) * has_trade          [gemm_ep<128,0>]
//  2. state  = scan_t( s = sigmoid(decay)*s + impact )              [3-phase chunked scan]
//  3. lob_enh = gelu(LN(concat(lob,state) @ lob_w.T + lob_b))       [gemm_ep<256,1>]
//  4. tr_enh  = gelu(LN(concat(trade,state) @ tr_w.T + tr_b))       [gemm_ep<256,1>]
//  5. q = lob_enh@wq.T+bq ; k,v = tr_enh@wk/wv.T+b                  [qkv_kernel]
//  6. ctx = softmax(qk^T/sqrt(32)) v  (flash, 64x64 tiles)          [attn_kernel]
//  7. fused = LN(lob_enh + ctx@out_w.T + out_b)                     [gemm_ep<128,2>]
//  8. out = gelu(LN(concat(fused,tr_enh) @ of_w.T + of_b))          [gemm_ep<256,1>]

#define B_  8
#define T_  2048
#define D_  128
#define NH_ 4

__device__ __forceinline__ float sigm(float x) { return 1.0f / (1.0f + __expf(-x)); }

// ---------------- generic row-block GEMM (8 rows/block, 256 thr) + epilogue ----
// c = tid&127 (output col), rh = tid>>7; thread handles rows rh, rh+2, rh+4, rh+6.
// EPI 0: tanh(LN)*extra[row]   EPI 1: gelu(LN)   EPI 2: LN(acc + extra[row][c])
template <int KTOT, int EPI>
__global__ __launch_bounds__(256) void gemm_ep(
    const float* __restrict__ X0, const float* __restrict__ X1,
    const float* __restrict__ W, const float* __restrict__ bias,
    const float* __restrict__ gamma, const float* __restrict__ beta,
    const float* __restrict__ extra, float* __restrict__ out)
{
    __shared__ float xs[8][KTOT];
    __shared__ float red[4][2][2][2];  // [i][rh][half][sum/sumsq]
    const int tid = threadIdx.x;
    const int c = tid & 127, rh = tid >> 7;
    const int rows0 = blockIdx.x * 8;
    {
        int r = tid >> 5, kq = tid & 31;
        *(float4*)&xs[r][kq * 4] =
            *(const float4*)(X0 + (size_t)(rows0 + r) * 128 + kq * 4);
        if constexpr (KTOT == 256) {
            *(float4*)&xs[r][128 + kq * 4] =
                *(const float4*)(X1 + (size_t)(rows0 + r) * 128 + kq * 4);
        }
    }
    __syncthreads();

    float acc[4];
    const float b0 = bias[c];
#pragma unroll
    for (int i = 0; i < 4; i++) acc[i] = b0;
    const float4* wr = (const float4*)(W + (size_t)c * KTOT);
#pragma unroll 8
    for (int kk = 0; kk < KTOT / 4; kk++) {
        const float4 wv = wr[kk];
#pragma unroll
        for (int i = 0; i < 4; i++) {
            const float4 xv = *(const float4*)&xs[rh + 2 * i][kk * 4];
            acc[i] = fmaf(xv.x, wv.x, acc[i]);
            acc[i] = fmaf(xv.y, wv.y, acc[i]);
            acc[i] = fmaf(xv.z, wv.z, acc[i]);
            acc[i] = fmaf(xv.w, wv.w, acc[i]);
        }
    }
    if constexpr (EPI == 2) {
#pragma unroll
        for (int i = 0; i < 4; i++)
            acc[i] += extra[(size_t)(rows0 + rh + 2 * i) * 128 + c];
    }
    // LN stats: reduce 128 cols spread over 2 waves
    const int half = c >> 6;
#pragma unroll
    for (int i = 0; i < 4; i++) {
        float s = acc[i], ss = acc[i] * acc[i];
#pragma unroll
        for (int o = 32; o; o >>= 1) { s += __shfl_xor(s, o); ss += __shfl_xor(ss, o); }
        if ((tid & 63) == 0) { red[i][rh][half][0] = s; red[i][rh][half][1] = ss; }
    }
    __syncthreads();
    const float gm = gamma[c], bt = beta[c];
#pragma unroll
    for (int i = 0; i < 4; i++) {
        const float S  = red[i][rh][0][0] + red[i][rh][1][0];
        const float SS = red[i][rh][0][1] + red[i][rh][1][1];
        const float mean = S * (1.0f / 128.0f);
        float var = SS * (1.0f / 128.0f) - mean * mean;
        var = fmaxf(var, 0.0f);
        float y = (acc[i] - mean) * rsqrtf(var + 1e-5f) * gm + bt;
        const int row = rows0 + rh + 2 * i;
        if constexpr (EPI == 0) y = tanhf(y) * extra[row];
        if constexpr (EPI == 1) y = 0.5f * y * (1.0f + erff(y * 0.70710678118654752f));
        out[(size_t)row * 128 + c] = y;
    }
}

// ---------------- qkv: 3 GEMMs (K=128, no LN), scatter to (B,NH,T,HD) --------
__global__ __launch_bounds__(256) void qkv_kernel(
    const float* __restrict__ lobe, const float* __restrict__ tre,
    const float* __restrict__ ipw, const float* __restrict__ ipb,
    float* __restrict__ qo, float* __restrict__ ko, float* __restrict__ vo)
{
    __shared__ float xs[8][128];
    const int tid = threadIdx.x;
    const int c = tid & 127, rh = tid >> 7;
    const int rows0 = blockIdx.x * 8;
    const int which = blockIdx.y;
    const float* X = (which == 0) ? lobe : tre;
    const float* W = ipw + (size_t)which * 128 * 128;
    {
        int r = tid >> 5, kq = tid & 31;
        *(float4*)&xs[r][kq * 4] =
            *(const float4*)(X + (size_t)(rows0 + r) * 128 + kq * 4);
    }
    __syncthreads();
    float acc[4];
    const float b0 = ipb[which * 128 + c];
#pragma unroll
    for (int i = 0; i < 4; i++) acc[i] = b0;
    const float4* wr = (const float4*)(W + (size_t)c * 128);
#pragma unroll 8
    for (int kk = 0; kk < 32; kk++) {
        const float4 wv = wr[kk];
#pragma unroll
        for (int i = 0; i < 4; i++) {
            const float4 xv = *(const float4*)&xs[rh + 2 * i][kk * 4];
            acc[i] = fmaf(xv.x, wv.x, acc[i]);
            acc[i] = fmaf(xv.y, wv.y, acc[i]);
            acc[i] = fmaf(xv.z, wv.z, acc[i]);
            acc[i] = fmaf(xv.w, wv.w, acc[i]);
        }
    }
    float* dst = (which == 0) ? qo : (which == 1 ? ko : vo);
    const int h = c >> 5, hd = c & 31;
#pragma unroll
    for (int i = 0; i < 4; i++) {
        const int row = rows0 + rh + 2 * i;
        const int b = row >> 11, t = row & 2047;
        dst[(((size_t)b * NH_ + h) * T_ + t) * 32 + hd] = acc[i];
    }
}

// ---------------- flash attention, f32, 64x64 tiles, online softmax ----------
__global__ __launch_bounds__(256) void attn_kernel(
    const float* __restrict__ q, const float* __restrict__ k,
    const float* __restrict__ v, float* __restrict__ ctx)
{
    __shared__ float qs[64][36], ks[64][36], vs[64][36];
    __shared__ float ps[64][65];
    const int tid = threadIdx.x;
    const int tx = tid & 15, ty = tid >> 4;
    const int qt = blockIdx.x;
    const int bh = blockIdx.y;
    const int b = bh >> 2, h = bh & 3;
    const float* qb = q + (size_t)bh * T_ * 32 + (size_t)qt * 64 * 32;
    const float* kb = k + (size_t)bh * T_ * 32;
    const float* vb = v + (size_t)bh * T_ * 32;
    const float SC = 0.17677669529663687f;  // 1/sqrt(32)
    {
        int r = tid >> 2, sg = tid & 3;
        const float4* s4 = (const float4*)(qb + r * 32 + sg * 8);
        float4 a = s4[0], bq = s4[1];
        a.x *= SC; a.y *= SC; a.z *= SC; a.w *= SC;
        bq.x *= SC; bq.y *= SC; bq.z *= SC; bq.w *= SC;
        *(float4*)&qs[r][sg * 8] = a;
        *(float4*)&qs[r][sg * 8 + 4] = bq;
    }
    float m_i[4], l_i[4], co[4][2];
#pragma unroll
    for (int i = 0; i < 4; i++) { m_i[i] = -1e30f; l_i[i] = 0.0f; co[i][0] = 0.0f; co[i][1] = 0.0f; }

    for (int kt = 0; kt < T_ / 64; kt++) {
        {
            int r = tid >> 2, sg = tid & 3;
            const float4* sk = (const float4*)(kb + (size_t)kt * 2048 + r * 32 + sg * 8);
            *(float4*)&ks[r][sg * 8]     = sk[0];
            *(float4*)&ks[r][sg * 8 + 4] = sk[1];
            const float4* sv = (const float4*)(vb + (size_t)kt * 2048 + r * 32 + sg * 8);
            *(float4*)&vs[r][sg * 8]     = sv[0];
            *(float4*)&vs[r][sg * 8 + 4] = sv[1];
        }
        __syncthreads();
        float s[4][4] = {{0.f,0.f,0.f,0.f},{0.f,0.f,0.f,0.f},{0.f,0.f,0.f,0.f},{0.f,0.f,0.f,0.f}};
#pragma unroll
        for (int kk = 0; kk < 8; kk++) {
            float4 qv[4], kv[4];
#pragma unroll
            for (int i = 0; i < 4; i++) qv[i] = *(const float4*)&qs[4 * ty + i][kk * 4];
#pragma unroll
            for (int j = 0; j < 4; j++) kv[j] = *(const float4*)&ks[4 * tx + j][kk * 4];
#pragma unroll
            for (int i = 0; i < 4; i++)
#pragma unroll
                for (int j = 0; j < 4; j++) {
                    s[i][j] = fmaf(qv[i].x, kv[j].x, s[i][j]);
                    s[i][j] = fmaf(qv[i].y, kv[j].y, s[i][j]);
                    s[i][j] = fmaf(qv[i].z, kv[j].z, s[i][j]);
                    s[i][j] = fmaf(qv[i].w, kv[j].w, s[i][j]);
                }
        }
#pragma unroll
        for (int i = 0; i < 4; i++) {
            float tm = fmaxf(fmaxf(s[i][0], s[i][1]), fmaxf(s[i][2], s[i][3]));
#pragma unroll
            for (int o = 8; o; o >>= 1) tm = fmaxf(tm, __shfl_xor(tm, o));
            const float mn = fmaxf(m_i[i], tm);
            const float alpha = __expf(m_i[i] - mn);
            float rs = 0.0f;
#pragma unroll
            for (int j = 0; j < 4; j++) {
                const float p = __expf(s[i][j] - mn);
                ps[4 * ty + i][4 * tx + j] = p;
                rs += p;
            }
#pragma unroll
            for (int o = 8; o; o >>= 1) rs += __shfl_xor(rs, o);
            l_i[i] = l_i[i] * alpha + rs;
            m_i[i] = mn;
            co[i][0] *= alpha; co[i][1] *= alpha;
        }
        __syncthreads();
#pragma unroll 8
        for (int kv = 0; kv < 64; kv++) {
            const float2 vv = *(const float2*)&vs[kv][2 * tx];
#pragma unroll
            for (int i = 0; i < 4; i++) {
                const float p = ps[4 * ty + i][kv];
                co[i][0] = fmaf(p, vv.x, co[i][0]);
                co[i][1] = fmaf(p, vv.y, co[i][1]);
            }
        }
        __syncthreads();
    }
#pragma unroll
    for (int i = 0; i < 4; i++) {
        const float inv = 1.0f / l_i[i];
        const int t = qt * 64 + 4 * ty + i;
        float* dst = ctx + ((size_t)(b * T_ + t)) * 128 + h * 32 + 2 * tx;
        dst[0] = co[i][0] * inv;
        dst[1] = co[i][1] * inv;
    }
}

// ---------------- decay scan: 3-phase chunked (32 chunks of 64) --------------
__global__ void scan_local_kernel(float* __restrict__ st, const float* __restrict__ decay)
{
    const int c = threadIdx.x;
    const int ch = blockIdx.x, b = blockIdx.y;
    const float d = sigm(decay[c]);
    const size_t base = ((size_t)b * T_ + ch * 64) * 128 + c;
    float s = 0.0f;
#pragma unroll 4
    for (int tl = 0; tl < 64; tl++) {
        const float x = st[base + (size_t)tl * 128];
        s = fmaf(d, s, x);
        st[base + (size_t)tl * 128] = s;
    }
}

__global__ void scan_carry_kernel(const float* __restrict__ st, const float* __restrict__ decay,
                                  float* __restrict__ carry)
{
    const int c = threadIdx.x;
    const int b = blockIdx.x;
    const float d = sigm(decay[c]);
    float dl = d;
#pragma unroll
    for (int i = 0; i < 6; i++) dl *= dl;  // d^64
    float ends[32];
#pragma unroll
    for (int ch = 0; ch < 32; ch++)
        ends[ch] = st[((size_t)b * T_ + ch * 64 + 63) * 128 + c];
    float e = 0.0f;
#pragma unroll
    for (int ch = 0; ch < 32; ch++) {
        carry[((size_t)b * 32 + ch) * 128 + c] = e;
        e = fmaf(dl, e, ends[ch]);
    }
}

__global__ void scan_add_kernel(float* __restrict__ st, const float* __restrict__ decay,
                                const float* __restrict__ carry)
{
    const int c = threadIdx.x;
    const int ch = blockIdx.x, b = blockIdx.y;
    if (ch == 0) return;
    const float d = sigm(decay[c]);
    const float cr = carry[((size_t)b * 32 + ch) * 128 + c];
    const size_t base = ((size_t)b * T_ + ch * 64) * 128 + c;
    float p = d;
#pragma unroll 4
    for (int tl = 0; tl < 64; tl++) {
        st[base + (size_t)tl * 128] += p * cr;
        p *= d;
    }
}

extern "C" void kernel_launch(void* const* d_in, const int* in_sizes, int n_in,
                              void* d_out, int out_size, void* d_ws, size_t ws_size,
                              hipStream_t stream)
{
    const float* lob_feat   = (const float*)d_in[0];
    const float* trade_feat = (const float*)d_in[1];
    const float* has_trade  = (const float*)d_in[2];
    const float* ei_w       = (const float*)d_in[3];
    const float* ei_b       = (const float*)d_in[4];
    const float* ei_g       = (const float*)d_in[5];
    const float* ei_beta    = (const float*)d_in[6];
    const float* decay      = (const float*)d_in[7];
    const float* in_proj_w  = (const float*)d_in[8];
    const float* in_proj_b  = (const float*)d_in[9];
    const float* out_proj_w = (const float*)d_in[10];
    const float* out_proj_b = (const float*)d_in[11];
    const float* cn_g       = (const float*)d_in[12];
    const float* cn_b       = (const float*)d_in[13];
    const float* lob_w      = (const float*)d_in[14];
    const float* lob_b      = (const float*)d_in[15];
    const float* lob_g      = (const float*)d_in[16];
    const float* lob_beta   = (const float*)d_in[17];
    const float* tr_w       = (const float*)d_in[18];
    const float* tr_b       = (const float*)d_in[19];
    const float* tr_g       = (const float*)d_in[20];
    const float* tr_beta    = (const float*)d_in[21];
    const float* of_w       = (const float*)d_in[22];
    const float* of_b       = (const float*)d_in[23];
    const float* of_g       = (const float*)d_in[24];
    const float* of_beta    = (const float*)d_in[25];

    float* ws = (float*)d_ws;
    const size_t SZ = (size_t)16384 * 128;  // 2M floats, 8 MB
    float* state  = ws;            // impact -> (in-place) state_seq
    float* lobe   = ws + SZ;
    float* tre    = ws + 2 * SZ;
    float* qb     = ws + 3 * SZ;
    float* kb     = ws + 4 * SZ;
    float* vb     = ws + 5 * SZ;
    float* ctxb   = ws + 6 * SZ;
    float* fusedb = ws + 7 * SZ;
    float* carry  = ws + 8 * SZ;   // 8*32*128 floats

    const dim3 blk(256);
    const dim3 g2048(2048);

    // 1. impact
    gemm_ep<128, 0><<<g2048, blk, 0, stream>>>(trade_feat, nullptr, ei_w, ei_b, ei_g, ei_beta,
                                               has_trade, state);
    // 2. scan
    scan_local_kernel<<<dim3(32, 8), dim3(128), 0, stream>>>(state, decay);
    scan_carry_kernel<<<dim3(8), dim3(128), 0, stream>>>(state, decay, carry);
    scan_add_kernel<<<dim3(32, 8), dim3(128), 0, stream>>>(state, decay, carry);
    // 3/4. lob_enh, trade_enh
    gemm_ep<256, 1><<<g2048, blk, 0, stream>>>(lob_feat, state, lob_w, lob_b, lob_g, lob_beta,
                                               nullptr, lobe);
    gemm_ep<256, 1><<<g2048, blk, 0, stream>>>(trade_feat, state, tr_w, tr_b, tr_g, tr_beta,
                                               nullptr, tre);
    // 5. qkv
    qkv_kernel<<<dim3(2048, 3), blk, 0, stream>>>(lobe, tre, in_proj_w, in_proj_b, qb, kb, vb);
    // 6. attention
    attn_kernel<<<dim3(32, 32), blk, 0, stream>>>(qb, kb, vb, ctxb);
    // 7. fused = LN(lobe + ctx@outW.T + outb)
    gemm_ep<128, 2><<<g2048, blk, 0, stream>>>(ctxb, nullptr, out_proj_w, out_proj_b, cn_g, cn_b,
                                               lobe, fusedb);
    // 8. output
    gemm_ep<256, 1><<<g2048, blk, 0, stream>>>(fusedb, tre, of_w, of_b, of_g, of_beta,
                                               nullptr, (float*)d_out);
}

// Round 2
// 516.838 us; speedup vs baseline: 1.5306x; 1.5306x over previous
//
#include <hip/hip_runtime.h>
#include <math.h>

// B=8, T=2048, D=128, NH=4, HD=32. BT = 16384 rows.
// Round 2: attention rewritten with bf16 MFMA (16x16x32), flash-style.
// Everything else (f32 GEMM+LN kernels, scan, qkv) unchanged from round 1.

#define B_  8
#define T_  2048
#define D_  128
#define NH_ 4

typedef short bf16x8 __attribute__((ext_vector_type(8)));
typedef float f32x4  __attribute__((ext_vector_type(4)));

__device__ __forceinline__ float sigm(float x) { return 1.0f / (1.0f + __expf(-x)); }

__device__ __forceinline__ unsigned short f2bf(float x) {
    union { float f; unsigned u; } v; v.f = x;
    unsigned r = v.u + 0x7FFFu + ((v.u >> 16) & 1u);  // RNE
    return (unsigned short)(r >> 16);
}

// ---------------- generic row-block GEMM (8 rows/block, 256 thr) + epilogue ----
template <int KTOT, int EPI>
__global__ __launch_bounds__(256) void gemm_ep(
    const float* __restrict__ X0, const float* __restrict__ X1,
    const float* __restrict__ W, const float* __restrict__ bias,
    const float* __restrict__ gamma, const float* __restrict__ beta,
    const float* __restrict__ extra, float* __restrict__ out)
{
    __shared__ float xs[8][KTOT];
    __shared__ float red[4][2][2][2];
    const int tid = threadIdx.x;
    const int c = tid & 127, rh = tid >> 7;
    const int rows0 = blockIdx.x * 8;
    {
        int r = tid >> 5, kq = tid & 31;
        *(float4*)&xs[r][kq * 4] =
            *(const float4*)(X0 + (size_t)(rows0 + r) * 128 + kq * 4);
        if constexpr (KTOT == 256) {
            *(float4*)&xs[r][128 + kq * 4] =
                *(const float4*)(X1 + (size_t)(rows0 + r) * 128 + kq * 4);
        }
    }
    __syncthreads();

    float acc[4];
    const float b0 = bias[c];
#pragma unroll
    for (int i = 0; i < 4; i++) acc[i] = b0;
    const float4* wr = (const float4*)(W + (size_t)c * KTOT);
#pragma unroll 8
    for (int kk = 0; kk < KTOT / 4; kk++) {
        const float4 wv = wr[kk];
#pragma unroll
        for (int i = 0; i < 4; i++) {
            const float4 xv = *(const float4*)&xs[rh + 2 * i][kk * 4];
            acc[i] = fmaf(xv.x, wv.x, acc[i]);
            acc[i] = fmaf(xv.y, wv.y, acc[i]);
            acc[i] = fmaf(xv.z, wv.z, acc[i]);
            acc[i] = fmaf(xv.w, wv.w, acc[i]);
        }
    }
    if constexpr (EPI == 2) {
#pragma unroll
        for (int i = 0; i < 4; i++)
            acc[i] += extra[(size_t)(rows0 + rh + 2 * i) * 128 + c];
    }
    const int half = c >> 6;
#pragma unroll
    for (int i = 0; i < 4; i++) {
        float s = acc[i], ss = acc[i] * acc[i];
#pragma unroll
        for (int o = 32; o; o >>= 1) { s += __shfl_xor(s, o); ss += __shfl_xor(ss, o); }
        if ((tid & 63) == 0) { red[i][rh][half][0] = s; red[i][rh][half][1] = ss; }
    }
    __syncthreads();
    const float gm = gamma[c], bt = beta[c];
#pragma unroll
    for (int i = 0; i < 4; i++) {
        const float S  = red[i][rh][0][0] + red[i][rh][1][0];
        const float SS = red[i][rh][0][1] + red[i][rh][1][1];
        const float mean = S * (1.0f / 128.0f);
        float var = SS * (1.0f / 128.0f) - mean * mean;
        var = fmaxf(var, 0.0f);
        float y = (acc[i] - mean) * rsqrtf(var + 1e-5f) * gm + bt;
        const int row = rows0 + rh + 2 * i;
        if constexpr (EPI == 0) y = tanhf(y) * extra[row];
        if constexpr (EPI == 1) y = 0.5f * y * (1.0f + erff(y * 0.70710678118654752f));
        out[(size_t)row * 128 + c] = y;
    }
}

// ---------------- qkv: 3 GEMMs (K=128, no LN), scatter to (B,NH,T,HD) --------
__global__ __launch_bounds__(256) void qkv_kernel(
    const float* __restrict__ lobe, const float* __restrict__ tre,
    const float* __restrict__ ipw, const float* __restrict__ ipb,
    float* __restrict__ qo, float* __restrict__ ko, float* __restrict__ vo)
{
    __shared__ float xs[8][128];
    const int tid = threadIdx.x;
    const int c = tid & 127, rh = tid >> 7;
    const int rows0 = blockIdx.x * 8;
    const int which = blockIdx.y;
    const float* X = (which == 0) ? lobe : tre;
    const float* W = ipw + (size_t)which * 128 * 128;
    {
        int r = tid >> 5, kq = tid & 31;
        *(float4*)&xs[r][kq * 4] =
            *(const float4*)(X + (size_t)(rows0 + r) * 128 + kq * 4);
    }
    __syncthreads();
    float acc[4];
    const float b0 = ipb[which * 128 + c];
#pragma unroll
    for (int i = 0; i < 4; i++) acc[i] = b0;
    const float4* wr = (const float4*)(W + (size_t)c * 128);
#pragma unroll 8
    for (int kk = 0; kk < 32; kk++) {
        const float4 wv = wr[kk];
#pragma unroll
        for (int i = 0; i < 4; i++) {
            const float4 xv = *(const float4*)&xs[rh + 2 * i][kk * 4];
            acc[i] = fmaf(xv.x, wv.x, acc[i]);
            acc[i] = fmaf(xv.y, wv.y, acc[i]);
            acc[i] = fmaf(xv.z, wv.z, acc[i]);
            acc[i] = fmaf(xv.w, wv.w, acc[i]);
        }
    }
    float* dst = (which == 0) ? qo : (which == 1 ? ko : vo);
    const int h = c >> 5, hd = c & 31;
#pragma unroll
    for (int i = 0; i < 4; i++) {
        const int row = rows0 + rh + 2 * i;
        const int b = row >> 11, t = row & 2047;
        dst[(((size_t)b * NH_ + h) * T_ + t) * 32 + hd] = acc[i];
    }
}

// ---------------- flash attention, bf16 MFMA 16x16x32 ------------------------
// Block: 256 thr = 4 waves; wave w owns q rows [qt*64 + w*16, +16).
// Q frag in regs (whole kernel). Per K-tile (64 keys): stage K (row-major,
// stride 40) + V^T (stride 72) as bf16 in LDS; QK^T = 4 MFMAs/wave; online
// softmax in regs (C layout: col=lane&15=key, row=4*(lane>>4)+r=q);
// P -> LDS bf16 (packed u32 writes); PV = 4 MFMAs/wave (A=P rows, B=V^T).
__global__ __launch_bounds__(256) void attn_kernel(
    const float* __restrict__ q, const float* __restrict__ k,
    const float* __restrict__ v, float* __restrict__ ctx)
{
    __shared__ unsigned short ks[64][40];   // K tile  [key][hd]
    __shared__ unsigned short vt[32][72];   // V^T     [d][key]
    __shared__ unsigned short ps[64][72];   // P tile  [q][key]

    const int tid  = threadIdx.x;
    const int wid  = tid >> 6;
    const int lane = tid & 63;
    const int c    = lane & 15;   // frag col / A-row index
    const int g    = lane >> 4;   // 16-lane group
    const int qt   = blockIdx.x;
    const int bh   = blockIdx.y;
    const int b    = bh >> 2, h = bh & 3;

    const float* kb_ = k + (size_t)bh * T_ * 32;
    const float* vb_ = v + (size_t)bh * T_ * 32;
    const float SC = 0.17677669529663687f;  // 1/sqrt(32)

    // Q fragment: row = wid*16 + c, k-elems g*8..g*8+7 (scaled, bf16)
    bf16x8 qf;
    {
        const float* qrow = q + (((size_t)bh * T_) + qt * 64 + wid * 16 + c) * 32 + g * 8;
        const float4 qa = *(const float4*)qrow;
        const float4 qb2 = *(const float4*)(qrow + 4);
        qf[0] = (short)f2bf(qa.x * SC); qf[1] = (short)f2bf(qa.y * SC);
        qf[2] = (short)f2bf(qa.z * SC); qf[3] = (short)f2bf(qa.w * SC);
        qf[4] = (short)f2bf(qb2.x * SC); qf[5] = (short)f2bf(qb2.y * SC);
        qf[6] = (short)f2bf(qb2.z * SC); qf[7] = (short)f2bf(qb2.w * SC);
    }

    float m_i[4], l_i[4];
    f32x4 acc[2];
#pragma unroll
    for (int r = 0; r < 4; r++) { m_i[r] = -1e30f; l_i[r] = 0.0f; }
    acc[0] = (f32x4){0.f, 0.f, 0.f, 0.f};
    acc[1] = (f32x4){0.f, 0.f, 0.f, 0.f};

    const int srow = tid >> 2, ssg = tid & 3;       // staging: row 0..63, 8-col group
    const bool evenc = (c & 1) == 0;
    const bool evenrow = ((srow & 1) == 0);

    for (int kt = 0; kt < T_ / 64; kt++) {
        // ---- issue global loads (f32) before barriers ----
        const float* kp = kb_ + ((size_t)kt * 64 + srow) * 32 + ssg * 8;
        const float4 ka = *(const float4*)kp;
        const float4 kbv = *(const float4*)(kp + 4);
        const float* vp = vb_ + ((size_t)kt * 64 + srow) * 32 + ssg * 8;
        const float4 va = *(const float4*)vp;
        const float4 vbv = *(const float4*)(vp + 4);

        __syncthreads();   // prev tile's LDS reads complete

        // K: row-major bf16, one b128 write
        {
            bf16x8 kk8;
            kk8[0] = (short)f2bf(ka.x);  kk8[1] = (short)f2bf(ka.y);
            kk8[2] = (short)f2bf(ka.z);  kk8[3] = (short)f2bf(ka.w);
            kk8[4] = (short)f2bf(kbv.x); kk8[5] = (short)f2bf(kbv.y);
            kk8[6] = (short)f2bf(kbv.z); kk8[7] = (short)f2bf(kbv.w);
            *(bf16x8*)&ks[srow][ssg * 8] = kk8;
        }
        // V transposed: pack rows (2r,2r+1) via shfl_xor(4), even rows write u32
        {
            float vv[8] = {va.x, va.y, va.z, va.w, vbv.x, vbv.y, vbv.z, vbv.w};
#pragma unroll
            for (int i = 0; i < 8; i++) {
                const float other = __shfl_xor(vv[i], 4);
                if (evenrow) {
                    const int d = ssg * 8 + i;
                    *(unsigned*)&vt[d][srow] =
                        (unsigned)f2bf(vv[i]) | ((unsigned)f2bf(other) << 16);
                }
            }
        }
        __syncthreads();   // staging visible

        // ---- QK^T: 4 MFMAs -> S[16q x 64key] per wave ----
        f32x4 s[4];
#pragma unroll
        for (int kb2 = 0; kb2 < 4; kb2++) {
            const bf16x8 kf = *(const bf16x8*)&ks[kb2 * 16 + c][g * 8];
            f32x4 z = (f32x4){0.f, 0.f, 0.f, 0.f};
            s[kb2] = __builtin_amdgcn_mfma_f32_16x16x32_bf16(qf, kf, z, 0, 0, 0);
        }

        // ---- online softmax (rows q = wid*16 + 4g + r) ----
        float alpha[4];
#pragma unroll
        for (int r = 0; r < 4; r++) {
            float tm = fmaxf(fmaxf(s[0][r], s[1][r]), fmaxf(s[2][r], s[3][r]));
#pragma unroll
            for (int o = 8; o; o >>= 1) tm = fmaxf(tm, __shfl_xor(tm, o));
            const float mn = fmaxf(m_i[r], tm);
            alpha[r] = __expf(m_i[r] - mn);
            m_i[r] = mn;
        }
        float rs[4] = {0.f, 0.f, 0.f, 0.f};
#pragma unroll
        for (int kb2 = 0; kb2 < 4; kb2++)
#pragma unroll
            for (int r = 0; r < 4; r++) {
                const float p = __expf(s[kb2][r] - m_i[r]);
                s[kb2][r] = p;
                rs[r] += p;
            }
#pragma unroll
        for (int r = 0; r < 4; r++) {
#pragma unroll
            for (int o = 8; o; o >>= 1) rs[r] += __shfl_xor(rs[r], o);
            l_i[r] = l_i[r] * alpha[r] + rs[r];
            acc[0][r] *= alpha[r];
            acc[1][r] *= alpha[r];
        }

        // ---- P -> LDS (bf16, packed u32 by even-c lanes) ----
#pragma unroll
        for (int kb2 = 0; kb2 < 4; kb2++)
#pragma unroll
            for (int r = 0; r < 4; r++) {
                const float pv2 = s[kb2][r];
                const float po = __shfl_xor(pv2, 1);
                if (evenc) {
                    *(unsigned*)&ps[wid * 16 + 4 * g + r][kb2 * 16 + c] =
                        (unsigned)f2bf(pv2) | ((unsigned)f2bf(po) << 16);
                }
            }
        // own rows only -> no barrier needed (compiler orders ds_write->ds_read)

        // ---- PV: A = P rows (wid*16+c), B = V^T ----
        const bf16x8 pa0 = *(const bf16x8*)&ps[wid * 16 + c][g * 8];
        const bf16x8 pa1 = *(const bf16x8*)&ps[wid * 16 + c][32 + g * 8];
#pragma unroll
        for (int nb = 0; nb < 2; nb++) {
            const bf16x8 v0 = *(const bf16x8*)&vt[nb * 16 + c][g * 8];
            const bf16x8 v1 = *(const bf16x8*)&vt[nb * 16 + c][32 + g * 8];
            acc[nb] = __builtin_amdgcn_mfma_f32_16x16x32_bf16(pa0, v0, acc[nb], 0, 0, 0);
            acc[nb] = __builtin_amdgcn_mfma_f32_16x16x32_bf16(pa1, v1, acc[nb], 0, 0, 0);
        }
    }

    // ---- epilogue: ctx[q][h*32 + d] = acc / l ----
#pragma unroll
    for (int r = 0; r < 4; r++) {
        const float inv = 1.0f / l_i[r];
        const int t = qt * 64 + wid * 16 + 4 * g + r;
        float* dst = ctx + ((size_t)(b * T_ + t)) * 128 + h * 32;
        dst[c]      = acc[0][r] * inv;
        dst[16 + c] = acc[1][r] * inv;
    }
}

// ---------------- decay scan: 3-phase chunked (32 chunks of 64) --------------
__global__ void scan_local_kernel(float* __restrict__ st, const float* __restrict__ decay)
{
    const int c = threadIdx.x;
    const int ch = blockIdx.x, b = blockIdx.y;
    const float d = sigm(decay[c]);
    const size_t base = ((size_t)b * T_ + ch * 64) * 128 + c;
    float s = 0.0f;
#pragma unroll 4
    for (int tl = 0; tl < 64; tl++) {
        const float x = st[base + (size_t)tl * 128];
        s = fmaf(d, s, x);
        st[base + (size_t)tl * 128] = s;
    }
}

__global__ void scan_carry_kernel(const float* __restrict__ st, const float* __restrict__ decay,
                                  float* __restrict__ carry)
{
    const int c = threadIdx.x;
    const int b = blockIdx.x;
    const float d = sigm(decay[c]);
    float dl = d;
#pragma unroll
    for (int i = 0; i < 6; i++) dl *= dl;  // d^64
    float ends[32];
#pragma unroll
    for (int ch = 0; ch < 32; ch++)
        ends[ch] = st[((size_t)b * T_ + ch * 64 + 63) * 128 + c];
    float e = 0.0f;
#pragma unroll
    for (int ch = 0; ch < 32; ch++) {
        carry[((size_t)b * 32 + ch) * 128 + c] = e;
        e = fmaf(dl, e, ends[ch]);
    }
}

__global__ void scan_add_kernel(float* __restrict__ st, const float* __restrict__ decay,
                                const float* __restrict__ carry)
{
    const int c = threadIdx.x;
    const int ch = blockIdx.x, b = blockIdx.y;
    if (ch == 0) return;
    const float d = sigm(decay[c]);
    const float cr = carry[((size_t)b * 32 + ch) * 128 + c];
    const size_t base = ((size_t)b * T_ + ch * 64) * 128 + c;
    float p = d;
#pragma unroll 4
    for (int tl = 0; tl < 64; tl++) {
        st[base + (size_t)tl * 128] += p * cr;
        p *= d;
    }
}

extern "C" void kernel_launch(void* const* d_in, const int* in_sizes, int n_in,
                              void* d_out, int out_size, void* d_ws, size_t ws_size,
                              hipStream_t stream)
{
    const float* lob_feat   = (const float*)d_in[0];
    const float* trade_feat = (const float*)d_in[1];
    const float* has_trade  = (const float*)d_in[2];
    const float* ei_w       = (const float*)d_in[3];
    const float* ei_b       = (const float*)d_in[4];
    const float* ei_g       = (const float*)d_in[5];
    const float* ei_beta    = (const float*)d_in[6];
    const float* decay      = (const float*)d_in[7];
    const float* in_proj_w  = (const float*)d_in[8];
    const float* in_proj_b  = (const float*)d_in[9];
    const float* out_proj_w = (const float*)d_in[10];
    const float* out_proj_b = (const float*)d_in[11];
    const float* cn_g       = (const float*)d_in[12];
    const float* cn_b       = (const float*)d_in[13];
    const float* lob_w      = (const float*)d_in[14];
    const float* lob_b      = (const float*)d_in[15];
    const float* lob_g      = (const float*)d_in[16];
    const float* lob_beta   = (const float*)d_in[17];
    const float* tr_w       = (const float*)d_in[18];
    const float* tr_b       = (const float*)d_in[19];
    const float* tr_g       = (const float*)d_in[20];
    const float* tr_beta    = (const float*)d_in[21];
    const float* of_w       = (const float*)d_in[22];
    const float* of_b       = (const float*)d_in[23];
    const float* of_g       = (const float*)d_in[24];
    const float* of_beta    = (const float*)d_in[25];

    float* ws = (float*)d_ws;
    const size_t SZ = (size_t)16384 * 128;  // 2M floats, 8 MB
    float* state  = ws;
    float* lobe   = ws + SZ;
    float* tre    = ws + 2 * SZ;
    float* qb     = ws + 3 * SZ;
    float* kb     = ws + 4 * SZ;
    float* vb     = ws + 5 * SZ;
    float* ctxb   = ws + 6 * SZ;
    float* fusedb = ws + 7 * SZ;
    float* carry  = ws + 8 * SZ;

    const dim3 blk(256);
    const dim3 g2048(2048);

    gemm_ep<128, 0><<<g2048, blk, 0, stream>>>(trade_feat, nullptr, ei_w, ei_b, ei_g, ei_beta,
                                               has_trade, state);
    scan_local_kernel<<<dim3(32, 8), dim3(128), 0, stream>>>(state, decay);
    scan_carry_kernel<<<dim3(8), dim3(128), 0, stream>>>(state, decay, carry);
    scan_add_kernel<<<dim3(32, 8), dim3(128), 0, stream>>>(state, decay, carry);
    gemm_ep<256, 1><<<g2048, blk, 0, stream>>>(lob_feat, state, lob_w, lob_b, lob_g, lob_beta,
                                               nullptr, lobe);
    gemm_ep<256, 1><<<g2048, blk, 0, stream>>>(trade_feat, state, tr_w, tr_b, tr_g, tr_beta,
                                               nullptr, tre);
    qkv_kernel<<<dim3(2048, 3), blk, 0, stream>>>(lobe, tre, in_proj_w, in_proj_b, qb, kb, vb);
    attn_kernel<<<dim3(32, 32), blk, 0, stream>>>(qb, kb, vb, ctxb);
    gemm_ep<128, 2><<<g2048, blk, 0, stream>>>(ctxb, nullptr, out_proj_w, out_proj_b, cn_g, cn_b,
                                               lobe, fusedb);
    gemm_ep<256, 1><<<g2048, blk, 0, stream>>>(fusedb, tre, of_w, of_b, of_g, of_beta,
                                               nullptr, (float*)d_out);
}

// Round 3
// 233.797 us; speedup vs baseline: 3.3836x; 2.2106x over previous
//
#include <hip/hip_runtime.h>
#include <math.h>

// B=8, T=2048, D=128, NH=4, HD=32. BT=16384 rows.
// Round 3: full bf16-MFMA pipeline.
//  prep:   weights + lob_feat/trade_feat -> bf16 pool
//  ei:     gemm_mfma<128,EPI0> -> state_f (f32)
//  scan:   local/carry/add(finalize -> state_bf)
//  lob:    gemm_mfma<256,EPI1> -> lobe_f (f32, residual) + lobe_bf
//  tr:     gemm_mfma<256,EPI1> -> tre_bf
//  qkv:    MFMA; Q prescaled bf16, K bf16, V transposed [bh][d][t] bf16
//  attn:   flash bf16 MFMA, exp2-domain softmax, cvt_pk P-pack
//  out:    gemm_mfma<128,EPI2> (residual lobe_f) -> fused_bf
//  of:     gemm_mfma<256,EPI1> -> d_out f32

#define T_  2048

typedef short bf16x8 __attribute__((ext_vector_type(8)));
typedef float f32x4  __attribute__((ext_vector_type(4)));
typedef unsigned short ushort_t;

__device__ __forceinline__ float sigm(float x) { return 1.0f / (1.0f + __expf(-x)); }

__device__ __forceinline__ unsigned short f2bf(float x) {
    union { float f; unsigned u; } v; v.f = x;
    unsigned r = v.u + 0x7FFFu + ((v.u >> 16) & 1u);  // RNE
    return (unsigned short)(r >> 16);
}

// ---------------- prep: f32 -> bf16 for inputs + all weights -----------------
// pool layout (elem offsets):
//  lob_feat 0..2097152, trade 2097152.., ei_w 4194304.., ipw 4210688..,
//  opw 4259840.., lob_w 4276224.., tr_w 4308992.., of_w 4341760..4374528
__global__ __launch_bounds__(256) void prep_kernel(
    const float* __restrict__ lob, const float* __restrict__ trade,
    const float* __restrict__ eiw, const float* __restrict__ ipw,
    const float* __restrict__ opw, const float* __restrict__ lobw,
    const float* __restrict__ trw, const float* __restrict__ ofw,
    ushort_t* __restrict__ pool)
{
    const size_t i8 = ((size_t)blockIdx.x * 256 + threadIdx.x) * 8;
    const float* src; size_t off;
    if      (i8 < 2097152) { src = lob;   off = 0; }
    else if (i8 < 4194304) { src = trade; off = 2097152; }
    else if (i8 < 4210688) { src = eiw;   off = 4194304; }
    else if (i8 < 4259840) { src = ipw;   off = 4210688; }
    else if (i8 < 4276224) { src = opw;   off = 4259840; }
    else if (i8 < 4308992) { src = lobw;  off = 4276224; }
    else if (i8 < 4341760) { src = trw;   off = 4308992; }
    else                   { src = ofw;   off = 4341760; }
    const float4 a = *(const float4*)(src + (i8 - off));
    const float4 b = *(const float4*)(src + (i8 - off) + 4);
    bf16x8 o;
    o[0] = (short)f2bf(a.x); o[1] = (short)f2bf(a.y);
    o[2] = (short)f2bf(a.z); o[3] = (short)f2bf(a.w);
    o[4] = (short)f2bf(b.x); o[5] = (short)f2bf(b.y);
    o[6] = (short)f2bf(b.z); o[7] = (short)f2bf(b.w);
    *(bf16x8*)(pool + i8) = o;
}

// ---------------- MFMA GEMM + LN + epilogue ----------------------------------
// Block 256 thr = 4 waves, tile 32 rows x 128 cols. Wave (rowblk=wid>>1,
// colhalf=wid&1): 16 rows x 64 cols = 4 col-blocks. Frags direct from global.
// EPI 0: tanh(LN)*extra[row]   1: gelu(LN)   2: LN(acc + extra[row][col])
template <int KTOT, int EPI, bool WF32, bool WBF>
__global__ __launch_bounds__(256) void gemm_mfma(
    const ushort_t* __restrict__ Xb0, const ushort_t* __restrict__ Xb1,
    const ushort_t* __restrict__ Wb,
    const float* __restrict__ bias, const float* __restrict__ gamma,
    const float* __restrict__ beta, const float* __restrict__ extra,
    float* __restrict__ outf, ushort_t* __restrict__ outb)
{
    __shared__ float red[32][2][2];
    const int tid = threadIdx.x, wid = tid >> 6, lane = tid & 63;
    const int c2 = lane & 15, g = lane >> 4;
    const int rowblk = wid >> 1, chf = wid & 1, cb0 = chf * 4;
    const int R0 = blockIdx.x * 32 + rowblk * 16;

    f32x4 acc[4] = {};
#pragma unroll
    for (int ch = 0; ch < KTOT / 32; ch++) {
        const ushort_t* xs = (KTOT == 256 && ch >= 4) ? Xb1 : Xb0;
        const int kk = (KTOT == 256 && ch >= 4) ? (ch - 4) * 32 : ch * 32;
        const bf16x8 a = *(const bf16x8*)(xs + (size_t)(R0 + c2) * 128 + kk + g * 8);
#pragma unroll
        for (int j = 0; j < 4; j++) {
            const bf16x8 b = *(const bf16x8*)(Wb + (size_t)((cb0 + j) * 16 + c2) * KTOT + ch * 32 + g * 8);
            acc[j] = __builtin_amdgcn_mfma_f32_16x16x32_bf16(a, b, acc[j], 0, 0, 0);
        }
    }
    float gm[4], bt[4];
#pragma unroll
    for (int j = 0; j < 4; j++) {
        const int col = (cb0 + j) * 16 + c2;
        const float bb = bias[col];
        gm[j] = gamma[col]; bt[j] = beta[col];
#pragma unroll
        for (int r = 0; r < 4; r++) acc[j][r] += bb;
    }
    if constexpr (EPI == 2) {
#pragma unroll
        for (int j = 0; j < 4; j++)
#pragma unroll
            for (int r = 0; r < 4; r++)
                acc[j][r] += extra[(size_t)(R0 + 4 * g + r) * 128 + (cb0 + j) * 16 + c2];
    }
#pragma unroll
    for (int r = 0; r < 4; r++) {
        float s = 0.f, ss = 0.f;
#pragma unroll
        for (int j = 0; j < 4; j++) { const float v = acc[j][r]; s += v; ss = fmaf(v, v, ss); }
#pragma unroll
        for (int o = 8; o; o >>= 1) { s += __shfl_xor(s, o); ss += __shfl_xor(ss, o); }
        if (c2 == 0) {
            red[rowblk * 16 + 4 * g + r][chf][0] = s;
            red[rowblk * 16 + 4 * g + r][chf][1] = ss;
        }
    }
    __syncthreads();
#pragma unroll
    for (int r = 0; r < 4; r++) {
        const int lr = rowblk * 16 + 4 * g + r;
        const float S  = red[lr][0][0] + red[lr][1][0];
        const float SS = red[lr][0][1] + red[lr][1][1];
        const float mean = S * (1.0f / 128.0f);
        float var = SS * (1.0f / 128.0f) - mean * mean;
        var = fmaxf(var, 0.0f);
        const float rstd = rsqrtf(var + 1e-5f);
        const int R = blockIdx.x * 32 + lr;
        const float ext = (EPI == 0) ? extra[R] : 0.0f;
#pragma unroll
        for (int j = 0; j < 4; j++) {
            float y = (acc[j][r] - mean) * rstd * gm[j] + bt[j];
            if constexpr (EPI == 0) y = tanhf(y) * ext;
            if constexpr (EPI == 1) y = 0.5f * y * (1.0f + erff(y * 0.70710678118654752f));
            const int col = (cb0 + j) * 16 + c2;
            if constexpr (WF32) outf[(size_t)R * 128 + col] = y;
            if constexpr (WBF)  outb[(size_t)R * 128 + col] = f2bf(y);
        }
    }
}

// ---------------- qkv MFMA: Q (prescaled), K, V^T ----------------------------
__global__ __launch_bounds__(256) void qkv_mfma(
    const ushort_t* __restrict__ lobe, const ushort_t* __restrict__ tre,
    const ushort_t* __restrict__ ipw, const float* __restrict__ ipb,
    ushort_t* __restrict__ qo, ushort_t* __restrict__ ko, ushort_t* __restrict__ vo)
{
    __shared__ ushort_t vls[128][36];
    const int tid = threadIdx.x, wid = tid >> 6, lane = tid & 63;
    const int c2 = lane & 15, g = lane >> 4;
    const int rowblk = wid >> 1, chf = wid & 1, cb0 = chf * 4;
    const int RB = blockIdx.x * 32;
    const int R0 = RB + rowblk * 16;
    const int which = blockIdx.y;
    const ushort_t* X = (which == 0) ? lobe : tre;
    const ushort_t* Wp = ipw + (size_t)which * 16384;

    f32x4 acc[4] = {};
#pragma unroll
    for (int ch = 0; ch < 4; ch++) {
        const bf16x8 a = *(const bf16x8*)(X + (size_t)(R0 + c2) * 128 + ch * 32 + g * 8);
#pragma unroll
        for (int j = 0; j < 4; j++) {
            const bf16x8 b = *(const bf16x8*)(Wp + (size_t)((cb0 + j) * 16 + c2) * 128 + ch * 32 + g * 8);
            acc[j] = __builtin_amdgcn_mfma_f32_16x16x32_bf16(a, b, acc[j], 0, 0, 0);
        }
    }
    // 1/sqrt(32) * log2(e): exp2-domain scores
    const float qscale = 0.17677669529663687f * 1.4426950408889634f;
    if (which < 2) {
        ushort_t* dst = (which == 0) ? qo : ko;
        const float sc = (which == 0) ? qscale : 1.0f;
#pragma unroll
        for (int j = 0; j < 4; j++) {
            const int col = (cb0 + j) * 16 + c2;
            const float bb = ipb[which * 128 + col];
            const int h = col >> 5, hd = col & 31;
#pragma unroll
            for (int r = 0; r < 4; r++) {
                const int R = R0 + 4 * g + r;
                const int b = R >> 11, t = R & 2047;
                dst[(((size_t)b * 4 + h) * 2048 + t) * 32 + hd] = f2bf((acc[j][r] + bb) * sc);
            }
        }
    } else {
#pragma unroll
        for (int j = 0; j < 4; j++) {
            const int col = (cb0 + j) * 16 + c2;
            const float bb = ipb[256 + col];
#pragma unroll
            for (int r = 0; r < 4; r++)
                vls[col][rowblk * 16 + 4 * g + r] = f2bf(acc[j][r] + bb);
        }
        __syncthreads();
        const int col = tid >> 1, hf = tid & 1;
        const int h = col >> 5, hd = col & 31;
        const int b = RB >> 11;
        unsigned w[8];
#pragma unroll
        for (int e = 0; e < 8; e++) w[e] = *(const unsigned*)&vls[col][hf * 16 + e * 2];
        ushort_t* dst = vo + (((size_t)b * 4 + h) * 32 + hd) * 2048 + (RB & 2047) + hf * 16;
        *(uint4*)dst       = *(const uint4*)&w[0];
        *(uint4*)(dst + 8) = *(const uint4*)&w[4];
    }
}

// ---------------- flash attention, bf16 MFMA, exp2-domain softmax ------------
__global__ __launch_bounds__(256) void attn_kernel(
    const ushort_t* __restrict__ q, const ushort_t* __restrict__ k,
    const ushort_t* __restrict__ vtg, ushort_t* __restrict__ ctx)
{
    __shared__ ushort_t ks[64][40];
    __shared__ ushort_t vt[32][72];
    __shared__ ushort_t ps[64][72];
    const int tid = threadIdx.x, wid = tid >> 6, lane = tid & 63;
    const int c = lane & 15, g = lane >> 4;
    const int qt = blockIdx.x, bh = blockIdx.y, b = bh >> 2, h = bh & 3;
    const ushort_t* kb_ = k   + (size_t)bh * 65536;
    const ushort_t* vb_ = vtg + (size_t)bh * 65536;

    const bf16x8 qf = *(const bf16x8*)(q + ((size_t)bh * 2048 + qt * 64 + wid * 16 + c) * 32 + g * 8);

    float m_i[4], l_i[4];
    f32x4 acc[2] = {};
#pragma unroll
    for (int r = 0; r < 4; r++) { m_i[r] = -1e30f; l_i[r] = 0.0f; }

    const int srow = tid >> 2, ssg = tid & 3;  // K staging
    const int vd = tid >> 3, vkg = tid & 7;    // V^T staging
    const bool evenc = !(c & 1);

    for (int kt = 0; kt < 32; kt++) {
        const bf16x8 kk8 = *(const bf16x8*)(kb_ + ((size_t)(kt * 64 + srow)) * 32 + ssg * 8);
        const bf16x8 vv8 = *(const bf16x8*)(vb_ + (size_t)vd * 2048 + kt * 64 + vkg * 8);
        __syncthreads();
        *(bf16x8*)&ks[srow][ssg * 8] = kk8;
        *(bf16x8*)&vt[vd][vkg * 8] = vv8;
        __syncthreads();

        f32x4 s[4];
#pragma unroll
        for (int kb2 = 0; kb2 < 4; kb2++) {
            const bf16x8 kf = *(const bf16x8*)&ks[kb2 * 16 + c][g * 8];
            f32x4 z = {};
            s[kb2] = __builtin_amdgcn_mfma_f32_16x16x32_bf16(qf, kf, z, 0, 0, 0);
        }
        float alpha[4];
#pragma unroll
        for (int r = 0; r < 4; r++) {
            float tm = fmaxf(fmaxf(s[0][r], s[1][r]), fmaxf(s[2][r], s[3][r]));
#pragma unroll
            for (int o = 8; o; o >>= 1) tm = fmaxf(tm, __shfl_xor(tm, o));
            const float mn = fmaxf(m_i[r], tm);
            alpha[r] = exp2f(m_i[r] - mn);
            m_i[r] = mn;
        }
        float rs[4] = {0.f, 0.f, 0.f, 0.f};
#pragma unroll
        for (int kb2 = 0; kb2 < 4; kb2++)
#pragma unroll
            for (int r = 0; r < 4; r++) {
                const float p = exp2f(s[kb2][r] - m_i[r]);
                s[kb2][r] = p;
                rs[r] += p;
            }
#pragma unroll
        for (int r = 0; r < 4; r++) {
#pragma unroll
            for (int o = 8; o; o >>= 1) rs[r] += __shfl_xor(rs[r], o);
            l_i[r] = l_i[r] * alpha[r] + rs[r];
            acc[0][r] *= alpha[r];
            acc[1][r] *= alpha[r];
        }
#pragma unroll
        for (int kb2 = 0; kb2 < 4; kb2++)
#pragma unroll
            for (int r = 0; r < 4; r++) {
                const float pv = s[kb2][r];
                const float po = __shfl_xor(pv, 1);
                if (evenc) {
                    unsigned pk;
                    asm("v_cvt_pk_bf16_f32 %0, %1, %2" : "=v"(pk) : "v"(pv), "v"(po));
                    *(unsigned*)&ps[wid * 16 + 4 * g + r][kb2 * 16 + c] = pk;
                }
            }
        const bf16x8 pa0 = *(const bf16x8*)&ps[wid * 16 + c][g * 8];
        const bf16x8 pa1 = *(const bf16x8*)&ps[wid * 16 + c][32 + g * 8];
#pragma unroll
        for (int nb = 0; nb < 2; nb++) {
            const bf16x8 v0 = *(const bf16x8*)&vt[nb * 16 + c][g * 8];
            const bf16x8 v1 = *(const bf16x8*)&vt[nb * 16 + c][32 + g * 8];
            acc[nb] = __builtin_amdgcn_mfma_f32_16x16x32_bf16(pa0, v0, acc[nb], 0, 0, 0);
            acc[nb] = __builtin_amdgcn_mfma_f32_16x16x32_bf16(pa1, v1, acc[nb], 0, 0, 0);
        }
    }
#pragma unroll
    for (int r = 0; r < 4; r++) {
        const float inv = 1.0f / l_i[r];
        const int t = qt * 64 + wid * 16 + 4 * g + r;
        ushort_t* dst = ctx + ((size_t)(b * 2048 + t)) * 128 + h * 32;
        dst[c]      = f2bf(acc[0][r] * inv);
        dst[16 + c] = f2bf(acc[1][r] * inv);
    }
}

// ---------------- decay scan -------------------------------------------------
__global__ void scan_local_kernel(float* __restrict__ st, const float* __restrict__ decay)
{
    const int c = threadIdx.x;
    const int ch = blockIdx.x, b = blockIdx.y;
    const float d = sigm(decay[c]);
    const size_t base = ((size_t)b * T_ + ch * 64) * 128 + c;
    float s = 0.0f;
#pragma unroll 4
    for (int tl = 0; tl < 64; tl++) {
        const float x = st[base + (size_t)tl * 128];
        s = fmaf(d, s, x);
        st[base + (size_t)tl * 128] = s;
    }
}

__global__ void scan_carry_kernel(const float* __restrict__ st, const float* __restrict__ decay,
                                  float* __restrict__ carry)
{
    const int c = threadIdx.x;
    const int b = blockIdx.x;
    const float d = sigm(decay[c]);
    float dl = d;
#pragma unroll
    for (int i = 0; i < 6; i++) dl *= dl;  // d^64
    float ends[32];
#pragma unroll
    for (int ch = 0; ch < 32; ch++)
        ends[ch] = st[((size_t)b * T_ + ch * 64 + 63) * 128 + c];
    float e = 0.0f;
#pragma unroll
    for (int ch = 0; ch < 32; ch++) {
        carry[((size_t)b * 32 + ch) * 128 + c] = e;
        e = fmaf(dl, e, ends[ch]);
    }
}

// adds carry and emits bf16 state (f32 state is dead afterwards)
__global__ void scan_fin_kernel(const float* __restrict__ st, const float* __restrict__ decay,
                                const float* __restrict__ carry, ushort_t* __restrict__ stbf)
{
    const int c = threadIdx.x;
    const int ch = blockIdx.x, b = blockIdx.y;
    const float d = sigm(decay[c]);
    const float cr = ch ? carry[((size_t)b * 32 + ch) * 128 + c] : 0.0f;
    const size_t base = ((size_t)b * T_ + ch * 64) * 128 + c;
    float p = d;
#pragma unroll 4
    for (int tl = 0; tl < 64; tl++) {
        const float s2 = st[base + (size_t)tl * 128] + p * cr;
        p *= d;
        stbf[base + (size_t)tl * 128] = f2bf(s2);
    }
}

extern "C" void kernel_launch(void* const* d_in, const int* in_sizes, int n_in,
                              void* d_out, int out_size, void* d_ws, size_t ws_size,
                              hipStream_t stream)
{
    const float* lob_feat   = (const float*)d_in[0];
    const float* trade_feat = (const float*)d_in[1];
    const float* has_trade  = (const float*)d_in[2];
    const float* ei_w       = (const float*)d_in[3];
    const float* ei_b       = (const float*)d_in[4];
    const float* ei_g       = (const float*)d_in[5];
    const float* ei_beta    = (const float*)d_in[6];
    const float* decay      = (const float*)d_in[7];
    const float* in_proj_w  = (const float*)d_in[8];
    const float* in_proj_b  = (const float*)d_in[9];
    const float* out_proj_w = (const float*)d_in[10];
    const float* out_proj_b = (const float*)d_in[11];
    const float* cn_g       = (const float*)d_in[12];
    const float* cn_b       = (const float*)d_in[13];
    const float* lob_w      = (const float*)d_in[14];
    const float* lob_b      = (const float*)d_in[15];
    const float* lob_g      = (const float*)d_in[16];
    const float* lob_beta   = (const float*)d_in[17];
    const float* tr_w       = (const float*)d_in[18];
    const float* tr_b       = (const float*)d_in[19];
    const float* tr_g       = (const float*)d_in[20];
    const float* tr_beta    = (const float*)d_in[21];
    const float* of_w       = (const float*)d_in[22];
    const float* of_b       = (const float*)d_in[23];
    const float* of_g       = (const float*)d_in[24];
    const float* of_beta    = (const float*)d_in[25];

    char* W = (char*)d_ws;
    const size_t MB = 1u << 20;
    float*    state_f  = (float*)W;                  // 8 MB, reused as lobe_f
    float*    lobe_f   = state_f;
    float*    carry    = (float*)(W + 8 * MB);       // 128 KB
    ushort_t* pool     = (ushort_t*)(W + 9 * MB);    // 8.75 MB
    ushort_t* state_bf = (ushort_t*)(W + 18 * MB);
    ushort_t* lobe_bf  = (ushort_t*)(W + 22 * MB);
    ushort_t* tre_bf   = (ushort_t*)(W + 26 * MB);
    ushort_t* q_bf     = (ushort_t*)(W + 30 * MB);
    ushort_t* k_bf     = (ushort_t*)(W + 34 * MB);
    ushort_t* vt_g     = (ushort_t*)(W + 38 * MB);
    ushort_t* ctx_bf   = (ushort_t*)(W + 42 * MB);
    ushort_t* fused_bf = (ushort_t*)(W + 46 * MB);

    ushort_t* lob_bf   = pool;
    ushort_t* trade_bf = pool + 2097152;
    ushort_t* eiw_bf   = pool + 4194304;
    ushort_t* ipw_bf   = pool + 4210688;
    ushort_t* opw_bf   = pool + 4259840;
    ushort_t* lobw_bf  = pool + 4276224;
    ushort_t* trw_bf   = pool + 4308992;
    ushort_t* ofw_bf   = pool + 4341760;

    const dim3 blk(256);

    prep_kernel<<<dim3(2136), blk, 0, stream>>>(lob_feat, trade_feat, ei_w, in_proj_w,
                                                out_proj_w, lob_w, tr_w, of_w, pool);
    // 1. impact -> state_f
    gemm_mfma<128, 0, true, false><<<dim3(512), blk, 0, stream>>>(
        trade_bf, nullptr, eiw_bf, ei_b, ei_g, ei_beta, has_trade, state_f, nullptr);
    // 2. scan -> state_bf
    scan_local_kernel<<<dim3(32, 8), dim3(128), 0, stream>>>(state_f, decay);
    scan_carry_kernel<<<dim3(8), dim3(128), 0, stream>>>(state_f, decay, carry);
    scan_fin_kernel<<<dim3(32, 8), dim3(128), 0, stream>>>(state_f, decay, carry, state_bf);
    // 3/4. lob_enh (f32+bf16), trade_enh (bf16)
    gemm_mfma<256, 1, true, true><<<dim3(512), blk, 0, stream>>>(
        lob_bf, state_bf, lobw_bf, lob_b, lob_g, lob_beta, nullptr, lobe_f, lobe_bf);
    gemm_mfma<256, 1, false, true><<<dim3(512), blk, 0, stream>>>(
        trade_bf, state_bf, trw_bf, tr_b, tr_g, tr_beta, nullptr, nullptr, tre_bf);
    // 5. qkv
    qkv_mfma<<<dim3(512, 3), blk, 0, stream>>>(lobe_bf, tre_bf, ipw_bf, in_proj_b,
                                               q_bf, k_bf, vt_g);
    // 6. attention
    attn_kernel<<<dim3(32, 32), blk, 0, stream>>>(q_bf, k_bf, vt_g, ctx_bf);
    // 7. fused = LN(lobe + ctx@outW.T + outb) -> fused_bf
    gemm_mfma<128, 2, false, true><<<dim3(512), blk, 0, stream>>>(
        ctx_bf, nullptr, opw_bf, out_proj_b, cn_g, cn_b, lobe_f, nullptr, fused_bf);
    // 8. output (f32)
    gemm_mfma<256, 1, true, false><<<dim3(512), blk, 0, stream>>>(
        fused_bf, tre_bf, ofw_bf, of_b, of_g, of_beta, nullptr, (float*)d_out, nullptr);
}

// Round 4
// 163.443 us; speedup vs baseline: 4.8400x; 1.4304x over previous
//
#include <hip/hip_runtime.h>
#include <math.h>

// B=8, T=2048, D=128, NH=4, HD=32. BT=16384 rows.
// Round 4: attn restructured — defer-max (fixed m, guarded), end-only sum
// reduction, shuffle-free P-pack, double-buffered K/V staging (1 barrier/tile).
// lob/tr GEMMs merged into one dispatch.

#define T_  2048

typedef short bf16x8 __attribute__((ext_vector_type(8)));
typedef float f32x4  __attribute__((ext_vector_type(4)));
typedef unsigned short ushort_t;

__device__ __forceinline__ float sigm(float x) { return 1.0f / (1.0f + __expf(-x)); }

__device__ __forceinline__ unsigned short f2bf(float x) {
    union { float f; unsigned u; } v; v.f = x;
    unsigned r = v.u + 0x7FFFu + ((v.u >> 16) & 1u);  // RNE
    return (unsigned short)(r >> 16);
}

// ---------------- prep: f32 -> bf16 for inputs + all weights -----------------
__global__ __launch_bounds__(256) void prep_kernel(
    const float* __restrict__ lob, const float* __restrict__ trade,
    const float* __restrict__ eiw, const float* __restrict__ ipw,
    const float* __restrict__ opw, const float* __restrict__ lobw,
    const float* __restrict__ trw, const float* __restrict__ ofw,
    ushort_t* __restrict__ pool)
{
    const size_t i8 = ((size_t)blockIdx.x * 256 + threadIdx.x) * 8;
    const float* src; size_t off;
    if      (i8 < 2097152) { src = lob;   off = 0; }
    else if (i8 < 4194304) { src = trade; off = 2097152; }
    else if (i8 < 4210688) { src = eiw;   off = 4194304; }
    else if (i8 < 4259840) { src = ipw;   off = 4210688; }
    else if (i8 < 4276224) { src = opw;   off = 4259840; }
    else if (i8 < 4308992) { src = lobw;  off = 4276224; }
    else if (i8 < 4341760) { src = trw;   off = 4308992; }
    else                   { src = ofw;   off = 4341760; }
    const float4 a = *(const float4*)(src + (i8 - off));
    const float4 b = *(const float4*)(src + (i8 - off) + 4);
    bf16x8 o;
    o[0] = (short)f2bf(a.x); o[1] = (short)f2bf(a.y);
    o[2] = (short)f2bf(a.z); o[3] = (short)f2bf(a.w);
    o[4] = (short)f2bf(b.x); o[5] = (short)f2bf(b.y);
    o[6] = (short)f2bf(b.z); o[7] = (short)f2bf(b.w);
    *(bf16x8*)(pool + i8) = o;
}

// ---------------- MFMA GEMM + LN + epilogue ----------------------------------
// Block 256 thr = 4 waves, tile 32 rows x 128 cols; frags direct from global.
// EPI 0: tanh(LN)*extra[row]   1: gelu(LN)   2: LN(acc + extra[row][col])
template <int KTOT, int EPI, bool WF32, bool WBF>
__global__ __launch_bounds__(256) void gemm_mfma(
    const ushort_t* __restrict__ Xb0, const ushort_t* __restrict__ Xb1,
    const ushort_t* __restrict__ Wb,
    const float* __restrict__ bias, const float* __restrict__ gamma,
    const float* __restrict__ beta, const float* __restrict__ extra,
    float* __restrict__ outf, ushort_t* __restrict__ outb)
{
    __shared__ float red[32][2][2];
    const int tid = threadIdx.x, wid = tid >> 6, lane = tid & 63;
    const int c2 = lane & 15, g = lane >> 4;
    const int rowblk = wid >> 1, chf = wid & 1, cb0 = chf * 4;
    const int R0 = blockIdx.x * 32 + rowblk * 16;

    f32x4 acc[4] = {};
#pragma unroll
    for (int ch = 0; ch < KTOT / 32; ch++) {
        const ushort_t* xs = (KTOT == 256 && ch >= 4) ? Xb1 : Xb0;
        const int kk = (KTOT == 256 && ch >= 4) ? (ch - 4) * 32 : ch * 32;
        const bf16x8 a = *(const bf16x8*)(xs + (size_t)(R0 + c2) * 128 + kk + g * 8);
#pragma unroll
        for (int j = 0; j < 4; j++) {
            const bf16x8 b = *(const bf16x8*)(Wb + (size_t)((cb0 + j) * 16 + c2) * KTOT + ch * 32 + g * 8);
            acc[j] = __builtin_amdgcn_mfma_f32_16x16x32_bf16(a, b, acc[j], 0, 0, 0);
        }
    }
    float gm[4], bt[4];
#pragma unroll
    for (int j = 0; j < 4; j++) {
        const int col = (cb0 + j) * 16 + c2;
        const float bb = bias[col];
        gm[j] = gamma[col]; bt[j] = beta[col];
#pragma unroll
        for (int r = 0; r < 4; r++) acc[j][r] += bb;
    }
    if constexpr (EPI == 2) {
#pragma unroll
        for (int j = 0; j < 4; j++)
#pragma unroll
            for (int r = 0; r < 4; r++)
                acc[j][r] += extra[(size_t)(R0 + 4 * g + r) * 128 + (cb0 + j) * 16 + c2];
    }
#pragma unroll
    for (int r = 0; r < 4; r++) {
        float s = 0.f, ss = 0.f;
#pragma unroll
        for (int j = 0; j < 4; j++) { const float v = acc[j][r]; s += v; ss = fmaf(v, v, ss); }
#pragma unroll
        for (int o = 8; o; o >>= 1) { s += __shfl_xor(s, o); ss += __shfl_xor(ss, o); }
        if (c2 == 0) {
            red[rowblk * 16 + 4 * g + r][chf][0] = s;
            red[rowblk * 16 + 4 * g + r][chf][1] = ss;
        }
    }
    __syncthreads();
#pragma unroll
    for (int r = 0; r < 4; r++) {
        const int lr = rowblk * 16 + 4 * g + r;
        const float S  = red[lr][0][0] + red[lr][1][0];
        const float SS = red[lr][0][1] + red[lr][1][1];
        const float mean = S * (1.0f / 128.0f);
        float var = SS * (1.0f / 128.0f) - mean * mean;
        var = fmaxf(var, 0.0f);
        const float rstd = rsqrtf(var + 1e-5f);
        const int R = blockIdx.x * 32 + lr;
        const float ext = (EPI == 0) ? extra[R] : 0.0f;
#pragma unroll
        for (int j = 0; j < 4; j++) {
            float y = (acc[j][r] - mean) * rstd * gm[j] + bt[j];
            if constexpr (EPI == 0) y = tanhf(y) * ext;
            if constexpr (EPI == 1) y = 0.5f * y * (1.0f + erff(y * 0.70710678118654752f));
            const int col = (cb0 + j) * 16 + c2;
            if constexpr (WF32) outf[(size_t)R * 128 + col] = y;
            if constexpr (WBF)  outb[(size_t)R * 128 + col] = f2bf(y);
        }
    }
}

// ---- dual-batch variant of gemm_mfma<256,1>: y=0 -> set A (also f32 out), y=1 -> set B
__global__ __launch_bounds__(256) void gemm_dual(
    const ushort_t* __restrict__ XA0, const ushort_t* __restrict__ XB0,
    const ushort_t* __restrict__ X1,
    const ushort_t* __restrict__ WA, const ushort_t* __restrict__ WB,
    const float* __restrict__ biasA, const float* __restrict__ biasB,
    const float* __restrict__ gA, const float* __restrict__ gB,
    const float* __restrict__ bA, const float* __restrict__ bB,
    float* __restrict__ outfA, ushort_t* __restrict__ outbA, ushort_t* __restrict__ outbB)
{
    __shared__ float red[32][2][2];
    const int sel = blockIdx.y;
    const ushort_t* Xb0 = sel ? XB0 : XA0;
    const ushort_t* Wb  = sel ? WB  : WA;
    const float* bias = sel ? biasB : biasA;
    const float* gamma = sel ? gB : gA;
    const float* beta  = sel ? bB : bA;
    ushort_t* outb = sel ? outbB : outbA;

    const int tid = threadIdx.x, wid = tid >> 6, lane = tid & 63;
    const int c2 = lane & 15, g = lane >> 4;
    const int rowblk = wid >> 1, chf = wid & 1, cb0 = chf * 4;
    const int R0 = blockIdx.x * 32 + rowblk * 16;

    f32x4 acc[4] = {};
#pragma unroll
    for (int ch = 0; ch < 8; ch++) {
        const ushort_t* xs = (ch >= 4) ? X1 : Xb0;
        const int kk = (ch >= 4) ? (ch - 4) * 32 : ch * 32;
        const bf16x8 a = *(const bf16x8*)(xs + (size_t)(R0 + c2) * 128 + kk + g * 8);
#pragma unroll
        for (int j = 0; j < 4; j++) {
            const bf16x8 b = *(const bf16x8*)(Wb + (size_t)((cb0 + j) * 16 + c2) * 256 + ch * 32 + g * 8);
            acc[j] = __builtin_amdgcn_mfma_f32_16x16x32_bf16(a, b, acc[j], 0, 0, 0);
        }
    }
    float gm[4], bt[4];
#pragma unroll
    for (int j = 0; j < 4; j++) {
        const int col = (cb0 + j) * 16 + c2;
        const float bb = bias[col];
        gm[j] = gamma[col]; bt[j] = beta[col];
#pragma unroll
        for (int r = 0; r < 4; r++) acc[j][r] += bb;
    }
#pragma unroll
    for (int r = 0; r < 4; r++) {
        float s = 0.f, ss = 0.f;
#pragma unroll
        for (int j = 0; j < 4; j++) { const float v = acc[j][r]; s += v; ss = fmaf(v, v, ss); }
#pragma unroll
        for (int o = 8; o; o >>= 1) { s += __shfl_xor(s, o); ss += __shfl_xor(ss, o); }
        if (c2 == 0) {
            red[rowblk * 16 + 4 * g + r][chf][0] = s;
            red[rowblk * 16 + 4 * g + r][chf][1] = ss;
        }
    }
    __syncthreads();
#pragma unroll
    for (int r = 0; r < 4; r++) {
        const int lr = rowblk * 16 + 4 * g + r;
        const float S  = red[lr][0][0] + red[lr][1][0];
        const float SS = red[lr][0][1] + red[lr][1][1];
        const float mean = S * (1.0f / 128.0f);
        float var = SS * (1.0f / 128.0f) - mean * mean;
        var = fmaxf(var, 0.0f);
        const float rstd = rsqrtf(var + 1e-5f);
        const int R = blockIdx.x * 32 + lr;
#pragma unroll
        for (int j = 0; j < 4; j++) {
            float y = (acc[j][r] - mean) * rstd * gm[j] + bt[j];
            y = 0.5f * y * (1.0f + erff(y * 0.70710678118654752f));
            const int col = (cb0 + j) * 16 + c2;
            if (!sel) outfA[(size_t)R * 128 + col] = y;
            outb[(size_t)R * 128 + col] = f2bf(y);
        }
    }
}

// ---------------- qkv MFMA: Q (prescaled), K, V^T ----------------------------
__global__ __launch_bounds__(256) void qkv_mfma(
    const ushort_t* __restrict__ lobe, const ushort_t* __restrict__ tre,
    const ushort_t* __restrict__ ipw, const float* __restrict__ ipb,
    ushort_t* __restrict__ qo, ushort_t* __restrict__ ko, ushort_t* __restrict__ vo)
{
    __shared__ ushort_t vls[128][36];
    const int tid = threadIdx.x, wid = tid >> 6, lane = tid & 63;
    const int c2 = lane & 15, g = lane >> 4;
    const int rowblk = wid >> 1, chf = wid & 1, cb0 = chf * 4;
    const int RB = blockIdx.x * 32;
    const int R0 = RB + rowblk * 16;
    const int which = blockIdx.y;
    const ushort_t* X = (which == 0) ? lobe : tre;
    const ushort_t* Wp = ipw + (size_t)which * 16384;

    f32x4 acc[4] = {};
#pragma unroll
    for (int ch = 0; ch < 4; ch++) {
        const bf16x8 a = *(const bf16x8*)(X + (size_t)(R0 + c2) * 128 + ch * 32 + g * 8);
#pragma unroll
        for (int j = 0; j < 4; j++) {
            const bf16x8 b = *(const bf16x8*)(Wp + (size_t)((cb0 + j) * 16 + c2) * 128 + ch * 32 + g * 8);
            acc[j] = __builtin_amdgcn_mfma_f32_16x16x32_bf16(a, b, acc[j], 0, 0, 0);
        }
    }
    const float qscale = 0.17677669529663687f * 1.4426950408889634f;
    if (which < 2) {
        ushort_t* dst = (which == 0) ? qo : ko;
        const float sc = (which == 0) ? qscale : 1.0f;
#pragma unroll
        for (int j = 0; j < 4; j++) {
            const int col = (cb0 + j) * 16 + c2;
            const float bb = ipb[which * 128 + col];
            const int h = col >> 5, hd = col & 31;
#pragma unroll
            for (int r = 0; r < 4; r++) {
                const int R = R0 + 4 * g + r;
                const int b = R >> 11, t = R & 2047;
                dst[(((size_t)b * 4 + h) * 2048 + t) * 32 + hd] = f2bf((acc[j][r] + bb) * sc);
            }
        }
    } else {
#pragma unroll
        for (int j = 0; j < 4; j++) {
            const int col = (cb0 + j) * 16 + c2;
            const float bb = ipb[256 + col];
#pragma unroll
            for (int r = 0; r < 4; r++)
                vls[col][rowblk * 16 + 4 * g + r] = f2bf(acc[j][r] + bb);
        }
        __syncthreads();
        const int col = tid >> 1, hf = tid & 1;
        const int h = col >> 5, hd = col & 31;
        const int b = RB >> 11;
        unsigned w[8];
#pragma unroll
        for (int e = 0; e < 8; e++) w[e] = *(const unsigned*)&vls[col][hf * 16 + e * 2];
        ushort_t* dst = vo + (((size_t)b * 4 + h) * 32 + hd) * 2048 + (RB & 2047) + hf * 16;
        *(uint4*)dst       = *(const uint4*)&w[0];
        *(uint4*)(dst + 8) = *(const uint4*)&w[4];
    }
}

// ---------------- flash attention, bf16 MFMA, defer-max softmax --------------
// 4 waves/block, 64 q-rows. One barrier/tile (double-buffered K/V staging).
// m fixed at 8 (exp2 domain); rescale path only if any score > m+40 (never for
// LN'd inputs, but correct if it fires). Per-lane partial sums reduced once.
__global__ __launch_bounds__(256) void attn_kernel(
    const ushort_t* __restrict__ q, const ushort_t* __restrict__ k,
    const ushort_t* __restrict__ vtg, ushort_t* __restrict__ ctx)
{
    __shared__ ushort_t ks[2][64][40];   // K tile   [buf][key][hd]
    __shared__ ushort_t vt[2][32][72];   // V^T tile [buf][d][key]
    __shared__ ushort_t ps[64][72];      // P        [q][key]
    const int tid = threadIdx.x, wid = tid >> 6, lane = tid & 63;
    const int c = lane & 15, g = lane >> 4;
    const int qt = blockIdx.x, bh = blockIdx.y, b = bh >> 2, h = bh & 3;
    const ushort_t* kb_ = k   + (size_t)bh * 65536;
    const ushort_t* vb_ = vtg + (size_t)bh * 65536;

    const bf16x8 qf = *(const bf16x8*)(q + ((size_t)bh * 2048 + qt * 64 + wid * 16 + c) * 32 + g * 8);

    float m_i[4], rs_[4];
    f32x4 acc[2] = {};
#pragma unroll
    for (int r = 0; r < 4; r++) { m_i[r] = 8.0f; rs_[r] = 0.0f; }

    const int srow = tid >> 2, ssg = tid & 3;  // K staging
    const int vd = tid >> 3, vkg = tid & 7;    // V^T staging

    // prologue: stage tile 0
    {
        const bf16x8 kk8 = *(const bf16x8*)(kb_ + (size_t)srow * 32 + ssg * 8);
        const bf16x8 vv8 = *(const bf16x8*)(vb_ + (size_t)vd * 2048 + vkg * 8);
        *(bf16x8*)&ks[0][srow][ssg * 8] = kk8;
        *(bf16x8*)&vt[0][vd][vkg * 8] = vv8;
    }
    __syncthreads();

    for (int kt = 0; kt < 32; kt++) {
        const int cur = kt & 1;
        // issue next-tile global loads early (latency hidden under compute)
        bf16x8 kk8, vv8;
        if (kt + 1 < 32) {
            kk8 = *(const bf16x8*)(kb_ + ((size_t)(kt + 1) * 64 + srow) * 32 + ssg * 8);
            vv8 = *(const bf16x8*)(vb_ + (size_t)vd * 2048 + (kt + 1) * 64 + vkg * 8);
        }

        // ---- QK^T: 4 MFMAs -> S[16q x 64key] per wave ----
        f32x4 s[4];
#pragma unroll
        for (int kb2 = 0; kb2 < 4; kb2++) {
            const bf16x8 kf = *(const bf16x8*)&ks[cur][kb2 * 16 + c][g * 8];
            f32x4 z = {};
            s[kb2] = __builtin_amdgcn_mfma_f32_16x16x32_bf16(qf, kf, z, 0, 0, 0);
        }

        // ---- guard: rescale only if scores approach overflow (rare) ----
        int need = 0;
        float lmax[4];
#pragma unroll
        for (int r = 0; r < 4; r++) {
            lmax[r] = fmaxf(fmaxf(s[0][r], s[1][r]), fmaxf(s[2][r], s[3][r]));
            need |= (lmax[r] > m_i[r] + 40.0f) ? 1 : 0;
        }
        if (__any(need)) {
#pragma unroll
            for (int r = 0; r < 4; r++) {
                float tm = lmax[r];
#pragma unroll
                for (int o = 8; o; o >>= 1) tm = fmaxf(tm, __shfl_xor(tm, o));
                const float mn = fmaxf(m_i[r], tm);
                const float al = exp2f(m_i[r] - mn);
                rs_[r] *= al; acc[0][r] *= al; acc[1][r] *= al;
                m_i[r] = mn;
            }
        }

        // ---- p = exp2(s - m); partial sums; P -> LDS (b16 scalar writes) ----
#pragma unroll
        for (int r = 0; r < 4; r++) {
            const float p0 = exp2f(s[0][r] - m_i[r]);
            const float p1 = exp2f(s[1][r] - m_i[r]);
            const float p2 = exp2f(s[2][r] - m_i[r]);
            const float p3 = exp2f(s[3][r] - m_i[r]);
            rs_[r] += (p0 + p1) + (p2 + p3);
            unsigned w01, w23;
            asm("v_cvt_pk_bf16_f32 %0, %1, %2" : "=v"(w01) : "v"(p0), "v"(p1));
            asm("v_cvt_pk_bf16_f32 %0, %1, %2" : "=v"(w23) : "v"(p2), "v"(p3));
            ushort_t* prow = &ps[wid * 16 + 4 * g + r][c];
            prow[0]  = (ushort_t)w01;
            prow[16] = (ushort_t)(w01 >> 16);
            prow[32] = (ushort_t)w23;
            prow[48] = (ushort_t)(w23 >> 16);
        }

        // ---- PV: A = P rows (own wave's rows), B = V^T ----
        const bf16x8 pa0 = *(const bf16x8*)&ps[wid * 16 + c][g * 8];
        const bf16x8 pa1 = *(const bf16x8*)&ps[wid * 16 + c][32 + g * 8];
#pragma unroll
        for (int nb = 0; nb < 2; nb++) {
            const bf16x8 v0 = *(const bf16x8*)&vt[cur][nb * 16 + c][g * 8];
            const bf16x8 v1 = *(const bf16x8*)&vt[cur][nb * 16 + c][32 + g * 8];
            acc[nb] = __builtin_amdgcn_mfma_f32_16x16x32_bf16(pa0, v0, acc[nb], 0, 0, 0);
            acc[nb] = __builtin_amdgcn_mfma_f32_16x16x32_bf16(pa1, v1, acc[nb], 0, 0, 0);
        }

        // ---- write next tile to the other buffer, one barrier ----
        if (kt + 1 < 32) {
            *(bf16x8*)&ks[cur ^ 1][srow][ssg * 8] = kk8;
            *(bf16x8*)&vt[cur ^ 1][vd][vkg * 8] = vv8;
        }
        __syncthreads();
    }

    // ---- final sum reduce (once) + epilogue ----
#pragma unroll
    for (int r = 0; r < 4; r++) {
        float t = rs_[r];
#pragma unroll
        for (int o = 8; o; o >>= 1) t += __shfl_xor(t, o);
        const float inv = 1.0f / t;
        const int tq = qt * 64 + wid * 16 + 4 * g + r;
        ushort_t* dst = ctx + ((size_t)(b * 2048 + tq)) * 128 + h * 32;
        dst[c]      = f2bf(acc[0][r] * inv);
        dst[16 + c] = f2bf(acc[1][r] * inv);
    }
}

// ---------------- decay scan -------------------------------------------------
__global__ void scan_local_kernel(float* __restrict__ st, const float* __restrict__ decay)
{
    const int c = threadIdx.x;
    const int ch = blockIdx.x, b = blockIdx.y;
    const float d = sigm(decay[c]);
    const size_t base = ((size_t)b * T_ + ch * 64) * 128 + c;
    float s = 0.0f;
#pragma unroll 4
    for (int tl = 0; tl < 64; tl++) {
        const float x = st[base + (size_t)tl * 128];
        s = fmaf(d, s, x);
        st[base + (size_t)tl * 128] = s;
    }
}

__global__ void scan_carry_kernel(const float* __restrict__ st, const float* __restrict__ decay,
                                  float* __restrict__ carry)
{
    const int c = threadIdx.x;
    const int b = blockIdx.x;
    const float d = sigm(decay[c]);
    float dl = d;
#pragma unroll
    for (int i = 0; i < 6; i++) dl *= dl;  // d^64
    float ends[32];
#pragma unroll
    for (int ch = 0; ch < 32; ch++)
        ends[ch] = st[((size_t)b * T_ + ch * 64 + 63) * 128 + c];
    float e = 0.0f;
#pragma unroll
    for (int ch = 0; ch < 32; ch++) {
        carry[((size_t)b * 32 + ch) * 128 + c] = e;
        e = fmaf(dl, e, ends[ch]);
    }
}

__global__ void scan_fin_kernel(const float* __restrict__ st, const float* __restrict__ decay,
                                const float* __restrict__ carry, ushort_t* __restrict__ stbf)
{
    const int c = threadIdx.x;
    const int ch = blockIdx.x, b = blockIdx.y;
    const float d = sigm(decay[c]);
    const float cr = ch ? carry[((size_t)b * 32 + ch) * 128 + c] : 0.0f;
    const size_t base = ((size_t)b * T_ + ch * 64) * 128 + c;
    float p = d;
#pragma unroll 4
    for (int tl = 0; tl < 64; tl++) {
        const float s2 = st[base + (size_t)tl * 128] + p * cr;
        p *= d;
        stbf[base + (size_t)tl * 128] = f2bf(s2);
    }
}

extern "C" void kernel_launch(void* const* d_in, const int* in_sizes, int n_in,
                              void* d_out, int out_size, void* d_ws, size_t ws_size,
                              hipStream_t stream)
{
    const float* lob_feat   = (const float*)d_in[0];
    const float* trade_feat = (const float*)d_in[1];
    const float* has_trade  = (const float*)d_in[2];
    const float* ei_w       = (const float*)d_in[3];
    const float* ei_b       = (const float*)d_in[4];
    const float* ei_g       = (const float*)d_in[5];
    const float* ei_beta    = (const float*)d_in[6];
    const float* decay      = (const float*)d_in[7];
    const float* in_proj_w  = (const float*)d_in[8];
    const float* in_proj_b  = (const float*)d_in[9];
    const float* out_proj_w = (const float*)d_in[10];
    const float* out_proj_b = (const float*)d_in[11];
    const float* cn_g       = (const float*)d_in[12];
    const float* cn_b       = (const float*)d_in[13];
    const float* lob_w      = (const float*)d_in[14];
    const float* lob_b      = (const float*)d_in[15];
    const float* lob_g      = (const float*)d_in[16];
    const float* lob_beta   = (const float*)d_in[17];
    const float* tr_w       = (const float*)d_in[18];
    const float* tr_b       = (const float*)d_in[19];
    const float* tr_g       = (const float*)d_in[20];
    const float* tr_beta    = (const float*)d_in[21];
    const float* of_w       = (const float*)d_in[22];
    const float* of_b       = (const float*)d_in[23];
    const float* of_g       = (const float*)d_in[24];
    const float* of_beta    = (const float*)d_in[25];

    char* W = (char*)d_ws;
    const size_t MB = 1u << 20;
    float*    state_f  = (float*)W;                  // 8 MB, reused as lobe_f
    float*    lobe_f   = state_f;
    float*    carry    = (float*)(W + 8 * MB);
    ushort_t* pool     = (ushort_t*)(W + 9 * MB);
    ushort_t* state_bf = (ushort_t*)(W + 18 * MB);
    ushort_t* lobe_bf  = (ushort_t*)(W + 22 * MB);
    ushort_t* tre_bf   = (ushort_t*)(W + 26 * MB);
    ushort_t* q_bf     = (ushort_t*)(W + 30 * MB);
    ushort_t* k_bf     = (ushort_t*)(W + 34 * MB);
    ushort_t* vt_g     = (ushort_t*)(W + 38 * MB);
    ushort_t* ctx_bf   = (ushort_t*)(W + 42 * MB);
    ushort_t* fused_bf = (ushort_t*)(W + 46 * MB);

    ushort_t* lob_bf   = pool;
    ushort_t* trade_bf = pool + 2097152;
    ushort_t* eiw_bf   = pool + 4194304;
    ushort_t* ipw_bf   = pool + 4210688;
    ushort_t* opw_bf   = pool + 4259840;
    ushort_t* lobw_bf  = pool + 4276224;
    ushort_t* trw_bf   = pool + 4308992;
    ushort_t* ofw_bf   = pool + 4341760;

    const dim3 blk(256);

    prep_kernel<<<dim3(2136), blk, 0, stream>>>(lob_feat, trade_feat, ei_w, in_proj_w,
                                                out_proj_w, lob_w, tr_w, of_w, pool);
    // 1. impact -> state_f
    gemm_mfma<128, 0, true, false><<<dim3(512), blk, 0, stream>>>(
        trade_bf, nullptr, eiw_bf, ei_b, ei_g, ei_beta, has_trade, state_f, nullptr);
    // 2. scan -> state_bf
    scan_local_kernel<<<dim3(32, 8), dim3(128), 0, stream>>>(state_f, decay);
    scan_carry_kernel<<<dim3(8), dim3(128), 0, stream>>>(state_f, decay, carry);
    scan_fin_kernel<<<dim3(32, 8), dim3(128), 0, stream>>>(state_f, decay, carry, state_bf);
    // 3/4. lob_enh + trade_enh in one dispatch
    gemm_dual<<<dim3(512, 2), blk, 0, stream>>>(
        lob_bf, trade_bf, state_bf, lobw_bf, trw_bf, lob_b, tr_b,
        lob_g, tr_g, lob_beta, tr_beta, lobe_f, lobe_bf, tre_bf);
    // 5. qkv
    qkv_mfma<<<dim3(512, 3), blk, 0, stream>>>(lobe_bf, tre_bf, ipw_bf, in_proj_b,
                                               q_bf, k_bf, vt_g);
    // 6. attention
    attn_kernel<<<dim3(32, 32), blk, 0, stream>>>(q_bf, k_bf, vt_g, ctx_bf);
    // 7. fused = LN(lobe + ctx@outW.T + outb) -> fused_bf
    gemm_mfma<128, 2, false, true><<<dim3(512), blk, 0, stream>>>(
        ctx_bf, nullptr, opw_bf, out_proj_b, cn_g, cn_b, lobe_f, nullptr, fused_bf);
    // 8. output (f32)
    gemm_mfma<256, 1, true, false><<<dim3(512), blk, 0, stream>>>(
        fused_bf, tre_bf, ofw_bf, of_b, of_g, of_beta, nullptr, (float*)d_out, nullptr);
}

// Round 5
// 149.360 us; speedup vs baseline: 5.2964x; 1.0943x over previous
//
#include <hip/hip_runtime.h>
#include <math.h>

// B=8, T=2048, D=128, NH=4, HD=32. BT=16384 rows.
// Round 5: fast activations (exp2+rcp), fused enh+qkv and outproj+final
// kernels (8 dispatches total), attn P-write as packed b32 via permuted
// key layout (pi: (c,c+16)->(2c,2c+1) per 64-tile), s_setprio on MFMA.

#define T_  2048

typedef short bf16x8 __attribute__((ext_vector_type(8)));
typedef float f32x4  __attribute__((ext_vector_type(4)));
typedef unsigned short ushort_t;

__device__ __forceinline__ float sigm(float x) { return 1.0f / (1.0f + __expf(-x)); }

__device__ __forceinline__ unsigned short f2bf(float x) {
    union { float f; unsigned u; } v; v.f = x;
    unsigned r = v.u + 0x7FFFu + ((v.u >> 16) & 1u);  // RNE
    return (unsigned short)(r >> 16);
}

// gelu(x) ~= x * sigmoid(2*0.79788456*(x+0.044715x^3)); exp2-domain, 1 rcp.
__device__ __forceinline__ float gelu_f(float x) {
    const float e = exp2f(fmaf(0.044715f * x, x * x, x) * -2.3022083f);
    return x * __builtin_amdgcn_rcpf(1.0f + e);
}
// tanh(y) = 1 - 2/(exp2(y*2*log2e)+1)  (exact identity; inf-safe)
__device__ __forceinline__ float tanh_f(float y) {
    const float e = exp2f(y * 2.8853900818f);
    return 1.0f - 2.0f * __builtin_amdgcn_rcpf(e + 1.0f);
}

// ---------------- prep: f32 -> bf16 for inputs + all weights -----------------
__global__ __launch_bounds__(256) void prep_kernel(
    const float* __restrict__ lob, const float* __restrict__ trade,
    const float* __restrict__ eiw, const float* __restrict__ ipw,
    const float* __restrict__ opw, const float* __restrict__ lobw,
    const float* __restrict__ trw, const float* __restrict__ ofw,
    ushort_t* __restrict__ pool)
{
    const size_t i8 = ((size_t)blockIdx.x * 256 + threadIdx.x) * 8;
    const float* src; size_t off;
    if      (i8 < 2097152) { src = lob;   off = 0; }
    else if (i8 < 4194304) { src = trade; off = 2097152; }
    else if (i8 < 4210688) { src = eiw;   off = 4194304; }
    else if (i8 < 4259840) { src = ipw;   off = 4210688; }
    else if (i8 < 4276224) { src = opw;   off = 4259840; }
    else if (i8 < 4308992) { src = lobw;  off = 4276224; }
    else if (i8 < 4341760) { src = trw;   off = 4308992; }
    else                   { src = ofw;   off = 4341760; }
    const float4 a = *(const float4*)(src + (i8 - off));
    const float4 b = *(const float4*)(src + (i8 - off) + 4);
    bf16x8 o;
    o[0] = (short)f2bf(a.x); o[1] = (short)f2bf(a.y);
    o[2] = (short)f2bf(a.z); o[3] = (short)f2bf(a.w);
    o[4] = (short)f2bf(b.x); o[5] = (short)f2bf(b.y);
    o[6] = (short)f2bf(b.z); o[7] = (short)f2bf(b.w);
    *(bf16x8*)(pool + i8) = o;
}

// ---------------- ei GEMM + LN + tanh*extra ----------------------------------
__global__ __launch_bounds__(256) void gemm_ei(
    const ushort_t* __restrict__ Xb0, const ushort_t* __restrict__ Wb,
    const float* __restrict__ bias, const float* __restrict__ gamma,
    const float* __restrict__ beta, const float* __restrict__ extra,
    float* __restrict__ outf)
{
    __shared__ float red[32][2][2];
    const int tid = threadIdx.x, wid = tid >> 6, lane = tid & 63;
    const int c2 = lane & 15, g = lane >> 4;
    const int rowblk = wid >> 1, chf = wid & 1, cb0 = chf * 4;
    const int R0 = blockIdx.x * 32 + rowblk * 16;

    f32x4 acc[4] = {};
#pragma unroll
    for (int ch = 0; ch < 4; ch++) {
        const bf16x8 a = *(const bf16x8*)(Xb0 + (size_t)(R0 + c2) * 128 + ch * 32 + g * 8);
#pragma unroll
        for (int j = 0; j < 4; j++) {
            const bf16x8 b = *(const bf16x8*)(Wb + (size_t)((cb0 + j) * 16 + c2) * 128 + ch * 32 + g * 8);
            acc[j] = __builtin_amdgcn_mfma_f32_16x16x32_bf16(a, b, acc[j], 0, 0, 0);
        }
    }
    float gm[4], bt[4];
#pragma unroll
    for (int j = 0; j < 4; j++) {
        const int col = (cb0 + j) * 16 + c2;
        const float bb = bias[col];
        gm[j] = gamma[col]; bt[j] = beta[col];
#pragma unroll
        for (int r = 0; r < 4; r++) acc[j][r] += bb;
    }
#pragma unroll
    for (int r = 0; r < 4; r++) {
        float s = 0.f, ss = 0.f;
#pragma unroll
        for (int j = 0; j < 4; j++) { const float v = acc[j][r]; s += v; ss = fmaf(v, v, ss); }
#pragma unroll
        for (int o = 8; o; o >>= 1) { s += __shfl_xor(s, o); ss += __shfl_xor(ss, o); }
        if (c2 == 0) {
            red[rowblk * 16 + 4 * g + r][chf][0] = s;
            red[rowblk * 16 + 4 * g + r][chf][1] = ss;
        }
    }
    __syncthreads();
#pragma unroll
    for (int r = 0; r < 4; r++) {
        const int lr = rowblk * 16 + 4 * g + r;
        const float S  = red[lr][0][0] + red[lr][1][0];
        const float SS = red[lr][0][1] + red[lr][1][1];
        const float mean = S * (1.0f / 128.0f);
        float var = SS * (1.0f / 128.0f) - mean * mean;
        var = fmaxf(var, 0.0f);
        const float rstd = rsqrtf(var + 1e-5f);
        const int R = blockIdx.x * 32 + lr;
        const float ext = extra[R];
#pragma unroll
        for (int j = 0; j < 4; j++) {
            const float y = (acc[j][r] - mean) * rstd * gm[j] + bt[j];
            outf[(size_t)R * 128 + (cb0 + j) * 16 + c2] = tanh_f(y) * ext;
        }
    }
}

// ---------------- fused enh (lobe+tre) + qkv ---------------------------------
__global__ __launch_bounds__(256) void enh_qkv(
    const ushort_t* __restrict__ lobb, const ushort_t* __restrict__ trab,
    const ushort_t* __restrict__ stab,
    const ushort_t* __restrict__ lobw, const ushort_t* __restrict__ trw,
    const ushort_t* __restrict__ ipw, const float* __restrict__ ipb,
    const float* __restrict__ lob_b, const float* __restrict__ lob_g,
    const float* __restrict__ lob_beta,
    const float* __restrict__ tr_b, const float* __restrict__ tr_g,
    const float* __restrict__ tr_beta,
    float* __restrict__ lobe_f, ushort_t* __restrict__ tre_bf,
    ushort_t* __restrict__ qo, ushort_t* __restrict__ ko, ushort_t* __restrict__ vo)
{
    __shared__ ushort_t lob_t[32][136];
    __shared__ ushort_t tre_t[32][136];
    __shared__ ushort_t vls[128][36];
    __shared__ float red[32][2][4];  // [row][chf][sL,ssL,sT,ssT]
    const int tid = threadIdx.x, wid = tid >> 6, lane = tid & 63;
    const int c2 = lane & 15, g = lane >> 4;
    const int rowblk = wid >> 1, chf = wid & 1, cb0 = chf * 4;
    const int RB = blockIdx.x * 32;
    const int R0 = RB + rowblk * 16;

    // ---- phase A: lobe & tre enh GEMMs (K=256), interleaved ----
    f32x4 aL[4] = {}, aT[4] = {};
#pragma unroll
    for (int ch = 0; ch < 8; ch++) {
        const int kk = (ch & 3) * 32;
        bf16x8 xl, xt;
        if (ch < 4) {
            xl = *(const bf16x8*)(lobb + (size_t)(R0 + c2) * 128 + kk + g * 8);
            xt = *(const bf16x8*)(trab + (size_t)(R0 + c2) * 128 + kk + g * 8);
        } else {
            xl = *(const bf16x8*)(stab + (size_t)(R0 + c2) * 128 + kk + g * 8);
            xt = xl;
        }
#pragma unroll
        for (int j = 0; j < 4; j++) {
            const size_t wo = (size_t)((cb0 + j) * 16 + c2) * 256 + ch * 32 + g * 8;
            aL[j] = __builtin_amdgcn_mfma_f32_16x16x32_bf16(xl, *(const bf16x8*)(lobw + wo), aL[j], 0, 0, 0);
            aT[j] = __builtin_amdgcn_mfma_f32_16x16x32_bf16(xt, *(const bf16x8*)(trw + wo), aT[j], 0, 0, 0);
        }
    }
#pragma unroll
    for (int j = 0; j < 4; j++) {
        const int col = (cb0 + j) * 16 + c2;
        const float bL = lob_b[col], bT = tr_b[col];
#pragma unroll
        for (int r = 0; r < 4; r++) { aL[j][r] += bL; aT[j][r] += bT; }
    }
#pragma unroll
    for (int r = 0; r < 4; r++) {
        float sL = 0.f, ssL = 0.f, sT = 0.f, ssT = 0.f;
#pragma unroll
        for (int j = 0; j < 4; j++) {
            const float vL = aL[j][r], vT = aT[j][r];
            sL += vL; ssL = fmaf(vL, vL, ssL);
            sT += vT; ssT = fmaf(vT, vT, ssT);
        }
#pragma unroll
        for (int o = 8; o; o >>= 1) {
            sL += __shfl_xor(sL, o); ssL += __shfl_xor(ssL, o);
            sT += __shfl_xor(sT, o); ssT += __shfl_xor(ssT, o);
        }
        if (c2 == 0) {
            float* rd = red[rowblk * 16 + 4 * g + r][chf];
            rd[0] = sL; rd[1] = ssL; rd[2] = sT; rd[3] = ssT;
        }
    }
    __syncthreads();
#pragma unroll
    for (int r = 0; r < 4; r++) {
        const int lr = rowblk * 16 + 4 * g + r;
        const int R = RB + lr;
        const float SL  = red[lr][0][0] + red[lr][1][0];
        const float SSL = red[lr][0][1] + red[lr][1][1];
        const float ST  = red[lr][0][2] + red[lr][1][2];
        const float SST = red[lr][0][3] + red[lr][1][3];
        const float mL = SL * (1.0f / 128.0f), mT = ST * (1.0f / 128.0f);
        const float rL = rsqrtf(fmaxf(SSL * (1.0f / 128.0f) - mL * mL, 0.0f) + 1e-5f);
        const float rT = rsqrtf(fmaxf(SST * (1.0f / 128.0f) - mT * mT, 0.0f) + 1e-5f);
#pragma unroll
        for (int j = 0; j < 4; j++) {
            const int col = (cb0 + j) * 16 + c2;
            const float yL = gelu_f((aL[j][r] - mL) * rL * lob_g[col] + lob_beta[col]);
            const float yT = gelu_f((aT[j][r] - mT) * rT * tr_g[col] + tr_beta[col]);
            lobe_f[(size_t)R * 128 + col] = yL;
            lob_t[lr][col] = f2bf(yL);
            const ushort_t tb = f2bf(yT);
            tre_bf[(size_t)R * 128 + col] = tb;
            tre_t[lr][col] = tb;
        }
    }
    __syncthreads();

    // ---- phase B: q from lob_t, k/v from tre_t ----
    const float qscale = 0.17677669529663687f * 1.4426950408889634f;
#pragma unroll
    for (int which = 0; which < 3; which++) {
        const ushort_t (*src)[136] = (which == 0) ? lob_t : tre_t;
        const ushort_t* Wp = ipw + (size_t)which * 16384;
        f32x4 pa[4] = {};
#pragma unroll
        for (int ch = 0; ch < 4; ch++) {
            const bf16x8 a = *(const bf16x8*)&src[rowblk * 16 + c2][ch * 32 + g * 8];
#pragma unroll
            for (int j = 0; j < 4; j++) {
                const bf16x8 b = *(const bf16x8*)(Wp + (size_t)((cb0 + j) * 16 + c2) * 128 + ch * 32 + g * 8);
                pa[j] = __builtin_amdgcn_mfma_f32_16x16x32_bf16(a, b, pa[j], 0, 0, 0);
            }
        }
        if (which < 2) {
            ushort_t* dst = (which == 0) ? qo : ko;
            const float sc = (which == 0) ? qscale : 1.0f;
#pragma unroll
            for (int j = 0; j < 4; j++) {
                const int col = (cb0 + j) * 16 + c2;
                const float bb = ipb[which * 128 + col];
                const int h = col >> 5, hd = col & 31;
#pragma unroll
                for (int r = 0; r < 4; r++) {
                    const int R = R0 + 4 * g + r;
                    const int b = R >> 11, t = R & 2047;
                    dst[(((size_t)b * 4 + h) * 2048 + t) * 32 + hd] = f2bf((pa[j][r] + bb) * sc);
                }
            }
        } else {
#pragma unroll
            for (int j = 0; j < 4; j++) {
                const int col = (cb0 + j) * 16 + c2;
                const float bb = ipb[256 + col];
#pragma unroll
                for (int r = 0; r < 4; r++)
                    vls[col][rowblk * 16 + 4 * g + r] = f2bf(pa[j][r] + bb);
            }
        }
    }
    __syncthreads();
    // V^T global write, permuted: pair (local c', c'+16) -> columns (RB+2c', +1)
    {
        const int col = tid >> 1, hf = tid & 1;
        const int h = col >> 5, hd = col & 31;
        const int b = RB >> 11;
        unsigned w[8];
#pragma unroll
        for (int e = 0; e < 8; e++) {
            const int cp = hf * 8 + e;
            w[e] = (unsigned)vls[col][cp] | ((unsigned)vls[col][cp + 16] << 16);
        }
        ushort_t* dst = vo + (((size_t)b * 4 + h) * 32 + hd) * 2048 + (RB & 2047) + hf * 16;
        *(uint4*)dst       = *(const uint4*)&w[0];
        *(uint4*)(dst + 8) = *(const uint4*)&w[4];
    }
}

// ---------------- flash attention, bf16 MFMA, defer-max, permuted P/V -------
__global__ __launch_bounds__(256) void attn_kernel(
    const ushort_t* __restrict__ q, const ushort_t* __restrict__ k,
    const ushort_t* __restrict__ vtg, ushort_t* __restrict__ ctx)
{
    __shared__ ushort_t ks[2][64][40];   // K tile   [buf][key][hd]
    __shared__ ushort_t vt[2][32][72];   // V^T tile [buf][d][permkey]
    __shared__ ushort_t ps[64][72];      // P        [q][permkey]
    const int tid = threadIdx.x, wid = tid >> 6, lane = tid & 63;
    const int c = lane & 15, g = lane >> 4;
    const int qt = blockIdx.x, bh = blockIdx.y, b = bh >> 2, h = bh & 3;
    const ushort_t* kb_ = k   + (size_t)bh * 65536;
    const ushort_t* vb_ = vtg + (size_t)bh * 65536;

    const bf16x8 qf = *(const bf16x8*)(q + ((size_t)bh * 2048 + qt * 64 + wid * 16 + c) * 32 + g * 8);

    float m_i[4], rs_[4];
    f32x4 acc[2] = {};
#pragma unroll
    for (int r = 0; r < 4; r++) { m_i[r] = 8.0f; rs_[r] = 0.0f; }

    const int srow = tid >> 2, ssg = tid & 3;  // K staging
    const int vd = tid >> 3, vkg = tid & 7;    // V^T staging

    {
        const bf16x8 kk8 = *(const bf16x8*)(kb_ + (size_t)srow * 32 + ssg * 8);
        const bf16x8 vv8 = *(const bf16x8*)(vb_ + (size_t)vd * 2048 + vkg * 8);
        *(bf16x8*)&ks[0][srow][ssg * 8] = kk8;
        *(bf16x8*)&vt[0][vd][vkg * 8] = vv8;
    }
    __syncthreads();

    for (int kt = 0; kt < 32; kt++) {
        const int cur = kt & 1;
        bf16x8 kk8, vv8;
        if (kt + 1 < 32) {
            kk8 = *(const bf16x8*)(kb_ + ((size_t)(kt + 1) * 64 + srow) * 32 + ssg * 8);
            vv8 = *(const bf16x8*)(vb_ + (size_t)vd * 2048 + (kt + 1) * 64 + vkg * 8);
        }

        // ---- QK^T ----
        f32x4 s[4];
        __builtin_amdgcn_s_setprio(1);
#pragma unroll
        for (int kb2 = 0; kb2 < 4; kb2++) {
            const bf16x8 kf = *(const bf16x8*)&ks[cur][kb2 * 16 + c][g * 8];
            f32x4 z = {};
            s[kb2] = __builtin_amdgcn_mfma_f32_16x16x32_bf16(qf, kf, z, 0, 0, 0);
        }
        __builtin_amdgcn_s_setprio(0);

        // ---- overflow guard (rare path) ----
        int need = 0;
        float lmax[4];
#pragma unroll
        for (int r = 0; r < 4; r++) {
            lmax[r] = fmaxf(fmaxf(s[0][r], s[1][r]), fmaxf(s[2][r], s[3][r]));
            need |= (lmax[r] > m_i[r] + 40.0f) ? 1 : 0;
        }
        if (__any(need)) {
#pragma unroll
            for (int r = 0; r < 4; r++) {
                float tm = lmax[r];
#pragma unroll
                for (int o = 8; o; o >>= 1) tm = fmaxf(tm, __shfl_xor(tm, o));
                const float mn = fmaxf(m_i[r], tm);
                const float al = exp2f(m_i[r] - mn);
                rs_[r] *= al; acc[0][r] *= al; acc[1][r] *= al;
                m_i[r] = mn;
            }
        }

        // ---- p = exp2(s-m); P -> LDS as packed b32 (permuted cols) ----
#pragma unroll
        for (int r = 0; r < 4; r++) {
            const float p0 = exp2f(s[0][r] - m_i[r]);
            const float p1 = exp2f(s[1][r] - m_i[r]);
            const float p2 = exp2f(s[2][r] - m_i[r]);
            const float p3 = exp2f(s[3][r] - m_i[r]);
            rs_[r] += (p0 + p1) + (p2 + p3);
            unsigned w01, w23;
            asm("v_cvt_pk_bf16_f32 %0, %1, %2" : "=v"(w01) : "v"(p0), "v"(p1));
            asm("v_cvt_pk_bf16_f32 %0, %1, %2" : "=v"(w23) : "v"(p2), "v"(p3));
            ushort_t* prow = ps[wid * 16 + 4 * g + r];
            *(unsigned*)&prow[2 * c] = w01;
            *(unsigned*)&prow[32 + 2 * c] = w23;
        }

        // ---- PV ----
        const bf16x8 pa0 = *(const bf16x8*)&ps[wid * 16 + c][g * 8];
        const bf16x8 pa1 = *(const bf16x8*)&ps[wid * 16 + c][32 + g * 8];
        __builtin_amdgcn_s_setprio(1);
#pragma unroll
        for (int nb = 0; nb < 2; nb++) {
            const bf16x8 v0 = *(const bf16x8*)&vt[cur][nb * 16 + c][g * 8];
            const bf16x8 v1 = *(const bf16x8*)&vt[cur][nb * 16 + c][32 + g * 8];
            acc[nb] = __builtin_amdgcn_mfma_f32_16x16x32_bf16(pa0, v0, acc[nb], 0, 0, 0);
            acc[nb] = __builtin_amdgcn_mfma_f32_16x16x32_bf16(pa1, v1, acc[nb], 0, 0, 0);
        }
        __builtin_amdgcn_s_setprio(0);

        if (kt + 1 < 32) {
            *(bf16x8*)&ks[cur ^ 1][srow][ssg * 8] = kk8;
            *(bf16x8*)&vt[cur ^ 1][vd][vkg * 8] = vv8;
        }
        __syncthreads();
    }

#pragma unroll
    for (int r = 0; r < 4; r++) {
        float t = rs_[r];
#pragma unroll
        for (int o = 8; o; o >>= 1) t += __shfl_xor(t, o);
        const float inv = __builtin_amdgcn_rcpf(t);
        const int tq = qt * 64 + wid * 16 + 4 * g + r;
        ushort_t* dst = ctx + ((size_t)(b * 2048 + tq)) * 128 + h * 32;
        dst[c]      = f2bf(acc[0][r] * inv);
        dst[16 + c] = f2bf(acc[1][r] * inv);
    }
}

// ---------------- fused out-proj + residual-LN + final GEMM ------------------
__global__ __launch_bounds__(256) void out_fuse(
    const ushort_t* __restrict__ ctxb, const ushort_t* __restrict__ treb,
    const ushort_t* __restrict__ opw, const float* __restrict__ opb,
    const float* __restrict__ cn_g, const float* __restrict__ cn_b,
    const ushort_t* __restrict__ ofw, const float* __restrict__ of_b,
    const float* __restrict__ of_g, const float* __restrict__ of_beta,
    const float* __restrict__ lobe_f, float* __restrict__ out)
{
    __shared__ ushort_t fus_t[32][136];
    __shared__ float red[32][2][2];
    const int tid = threadIdx.x, wid = tid >> 6, lane = tid & 63;
    const int c2 = lane & 15, g = lane >> 4;
    const int rowblk = wid >> 1, chf = wid & 1, cb0 = chf * 4;
    const int RB = blockIdx.x * 32;
    const int R0 = RB + rowblk * 16;

    // ---- phase A: fused = LN(lobe + ctx@opw + opb) ----
    f32x4 acc[4] = {};
#pragma unroll
    for (int ch = 0; ch < 4; ch++) {
        const bf16x8 a = *(const bf16x8*)(ctxb + (size_t)(R0 + c2) * 128 + ch * 32 + g * 8);
#pragma unroll
        for (int j = 0; j < 4; j++) {
            const bf16x8 b = *(const bf16x8*)(opw + (size_t)((cb0 + j) * 16 + c2) * 128 + ch * 32 + g * 8);
            acc[j] = __builtin_amdgcn_mfma_f32_16x16x32_bf16(a, b, acc[j], 0, 0, 0);
        }
    }
#pragma unroll
    for (int j = 0; j < 4; j++) {
        const int col = (cb0 + j) * 16 + c2;
        const float bb = opb[col];
#pragma unroll
        for (int r = 0; r < 4; r++)
            acc[j][r] += bb + lobe_f[(size_t)(R0 + 4 * g + r) * 128 + col];
    }
#pragma unroll
    for (int r = 0; r < 4; r++) {
        float s = 0.f, ss = 0.f;
#pragma unroll
        for (int j = 0; j < 4; j++) { const float v = acc[j][r]; s += v; ss = fmaf(v, v, ss); }
#pragma unroll
        for (int o = 8; o; o >>= 1) { s += __shfl_xor(s, o); ss += __shfl_xor(ss, o); }
        if (c2 == 0) {
            red[rowblk * 16 + 4 * g + r][chf][0] = s;
            red[rowblk * 16 + 4 * g + r][chf][1] = ss;
        }
    }
    __syncthreads();
#pragma unroll
    for (int r = 0; r < 4; r++) {
        const int lr = rowblk * 16 + 4 * g + r;
        const float S  = red[lr][0][0] + red[lr][1][0];
        const float SS = red[lr][0][1] + red[lr][1][1];
        const float mean = S * (1.0f / 128.0f);
        const float rstd = rsqrtf(fmaxf(SS * (1.0f / 128.0f) - mean * mean, 0.0f) + 1e-5f);
#pragma unroll
        for (int j = 0; j < 4; j++) {
            const int col = (cb0 + j) * 16 + c2;
            fus_t[lr][col] = f2bf((acc[j][r] - mean) * rstd * cn_g[col] + cn_b[col]);
        }
    }
    __syncthreads();

    // ---- phase B: out = gelu(LN([fused, tre]@ofw + ofb)) ----
    f32x4 a2[4] = {};
#pragma unroll
    for (int ch = 0; ch < 8; ch++) {
        bf16x8 a;
        if (ch < 4) a = *(const bf16x8*)&fus_t[rowblk * 16 + c2][ch * 32 + g * 8];
        else        a = *(const bf16x8*)(treb + (size_t)(R0 + c2) * 128 + (ch - 4) * 32 + g * 8);
#pragma unroll
        for (int j = 0; j < 4; j++) {
            const bf16x8 b = *(const bf16x8*)(ofw + (size_t)((cb0 + j) * 16 + c2) * 256 + ch * 32 + g * 8);
            a2[j] = __builtin_amdgcn_mfma_f32_16x16x32_bf16(a, b, a2[j], 0, 0, 0);
        }
    }
#pragma unroll
    for (int j = 0; j < 4; j++) {
        const float bb = of_b[(cb0 + j) * 16 + c2];
#pragma unroll
        for (int r = 0; r < 4; r++) a2[j][r] += bb;
    }
#pragma unroll
    for (int r = 0; r < 4; r++) {
        float s = 0.f, ss = 0.f;
#pragma unroll
        for (int j = 0; j < 4; j++) { const float v = a2[j][r]; s += v; ss = fmaf(v, v, ss); }
#pragma unroll
        for (int o = 8; o; o >>= 1) { s += __shfl_xor(s, o); ss += __shfl_xor(ss, o); }
        if (c2 == 0) {
            red[rowblk * 16 + 4 * g + r][chf][0] = s;
            red[rowblk * 16 + 4 * g + r][chf][1] = ss;
        }
    }
    __syncthreads();
#pragma unroll
    for (int r = 0; r < 4; r++) {
        const int lr = rowblk * 16 + 4 * g + r;
        const float S  = red[lr][0][0] + red[lr][1][0];
        const float SS = red[lr][0][1] + red[lr][1][1];
        const float mean = S * (1.0f / 128.0f);
        const float rstd = rsqrtf(fmaxf(SS * (1.0f / 128.0f) - mean * mean, 0.0f) + 1e-5f);
        const int R = RB + lr;
#pragma unroll
        for (int j = 0; j < 4; j++) {
            const int col = (cb0 + j) * 16 + c2;
            const float y = (a2[j][r] - mean) * rstd * of_g[col] + of_beta[col];
            out[(size_t)R * 128 + col] = gelu_f(y);
        }
    }
}

// ---------------- decay scan -------------------------------------------------
__global__ void scan_local_kernel(float* __restrict__ st, const float* __restrict__ decay)
{
    const int c = threadIdx.x;
    const int ch = blockIdx.x, b = blockIdx.y;
    const float d = sigm(decay[c]);
    const size_t base = ((size_t)b * T_ + ch * 64) * 128 + c;
    float s = 0.0f;
#pragma unroll 4
    for (int tl = 0; tl < 64; tl++) {
        const float x = st[base + (size_t)tl * 128];
        s = fmaf(d, s, x);
        st[base + (size_t)tl * 128] = s;
    }
}

__global__ void scan_carry_kernel(const float* __restrict__ st, const float* __restrict__ decay,
                                  float* __restrict__ carry)
{
    const int c = threadIdx.x;
    const int b = blockIdx.x;
    const float d = sigm(decay[c]);
    float dl = d;
#pragma unroll
    for (int i = 0; i < 6; i++) dl *= dl;  // d^64
    float ends[32];
#pragma unroll
    for (int ch = 0; ch < 32; ch++)
        ends[ch] = st[((size_t)b * T_ + ch * 64 + 63) * 128 + c];
    float e = 0.0f;
#pragma unroll
    for (int ch = 0; ch < 32; ch++) {
        carry[((size_t)b * 32 + ch) * 128 + c] = e;
        e = fmaf(dl, e, ends[ch]);
    }
}

__global__ void scan_fin_kernel(const float* __restrict__ st, const float* __restrict__ decay,
                                const float* __restrict__ carry, ushort_t* __restrict__ stbf)
{
    const int c = threadIdx.x;
    const int ch = blockIdx.x, b = blockIdx.y;
    const float d = sigm(decay[c]);
    const float cr = ch ? carry[((size_t)b * 32 + ch) * 128 + c] : 0.0f;
    const size_t base = ((size_t)b * T_ + ch * 64) * 128 + c;
    float p = d;
#pragma unroll 4
    for (int tl = 0; tl < 64; tl++) {
        const float s2 = st[base + (size_t)tl * 128] + p * cr;
        p *= d;
        stbf[base + (size_t)tl * 128] = f2bf(s2);
    }
}

extern "C" void kernel_launch(void* const* d_in, const int* in_sizes, int n_in,
                              void* d_out, int out_size, void* d_ws, size_t ws_size,
                              hipStream_t stream)
{
    const float* lob_feat   = (const float*)d_in[0];
    const float* trade_feat = (const float*)d_in[1];
    const float* has_trade  = (const float*)d_in[2];
    const float* ei_w       = (const float*)d_in[3];
    const float* ei_b       = (const float*)d_in[4];
    const float* ei_g       = (const float*)d_in[5];
    const float* ei_beta    = (const float*)d_in[6];
    const float* decay      = (const float*)d_in[7];
    const float* in_proj_w  = (const float*)d_in[8];
    const float* in_proj_b  = (const float*)d_in[9];
    const float* out_proj_w = (const float*)d_in[10];
    const float* out_proj_b = (const float*)d_in[11];
    const float* cn_g       = (const float*)d_in[12];
    const float* cn_b       = (const float*)d_in[13];
    const float* lob_w      = (const float*)d_in[14];
    const float* lob_b      = (const float*)d_in[15];
    const float* lob_g      = (const float*)d_in[16];
    const float* lob_beta   = (const float*)d_in[17];
    const float* tr_w       = (const float*)d_in[18];
    const float* tr_b       = (const float*)d_in[19];
    const float* tr_g       = (const float*)d_in[20];
    const float* tr_beta    = (const float*)d_in[21];
    const float* of_w       = (const float*)d_in[22];
    const float* of_b       = (const float*)d_in[23];
    const float* of_g       = (const float*)d_in[24];
    const float* of_beta    = (const float*)d_in[25];

    char* W = (char*)d_ws;
    const size_t MB = 1u << 20;
    float*    state_f  = (float*)W;                  // 8 MB, reused as lobe_f
    float*    lobe_f   = state_f;
    float*    carry    = (float*)(W + 8 * MB);
    ushort_t* pool     = (ushort_t*)(W + 9 * MB);
    ushort_t* state_bf = (ushort_t*)(W + 18 * MB);
    ushort_t* tre_bf   = (ushort_t*)(W + 26 * MB);
    ushort_t* q_bf     = (ushort_t*)(W + 30 * MB);
    ushort_t* k_bf     = (ushort_t*)(W + 34 * MB);
    ushort_t* vt_g     = (ushort_t*)(W + 38 * MB);
    ushort_t* ctx_bf   = (ushort_t*)(W + 42 * MB);

    ushort_t* lob_bf   = pool;
    ushort_t* trade_bf = pool + 2097152;
    ushort_t* eiw_bf   = pool + 4194304;
    ushort_t* ipw_bf   = pool + 4210688;
    ushort_t* opw_bf   = pool + 4259840;
    ushort_t* lobw_bf  = pool + 4276224;
    ushort_t* trw_bf   = pool + 4308992;
    ushort_t* ofw_bf   = pool + 4341760;

    const dim3 blk(256);

    prep_kernel<<<dim3(2136), blk, 0, stream>>>(lob_feat, trade_feat, ei_w, in_proj_w,
                                                out_proj_w, lob_w, tr_w, of_w, pool);
    // 1. impact -> state_f
    gemm_ei<<<dim3(512), blk, 0, stream>>>(trade_bf, eiw_bf, ei_b, ei_g, ei_beta,
                                           has_trade, state_f);
    // 2. scan -> state_bf
    scan_local_kernel<<<dim3(32, 8), dim3(128), 0, stream>>>(state_f, decay);
    scan_carry_kernel<<<dim3(8), dim3(128), 0, stream>>>(state_f, decay, carry);
    scan_fin_kernel<<<dim3(32, 8), dim3(128), 0, stream>>>(state_f, decay, carry, state_bf);
    // 3. lob_enh + trade_enh + qkv (fused)
    enh_qkv<<<dim3(512), blk, 0, stream>>>(lob_bf, trade_bf, state_bf, lobw_bf, trw_bf,
                                           ipw_bf, in_proj_b, lob_b, lob_g, lob_beta,
                                           tr_b, tr_g, tr_beta, lobe_f, tre_bf,
                                           q_bf, k_bf, vt_g);
    // 4. attention
    attn_kernel<<<dim3(32, 32), blk, 0, stream>>>(q_bf, k_bf, vt_g, ctx_bf);
    // 5. out-proj + residual LN + final GEMM (fused)
    out_fuse<<<dim3(512), blk, 0, stream>>>(ctx_bf, tre_bf, opw_bf, out_proj_b, cn_g, cn_b,
                                            ofw_bf, of_b, of_g, of_beta, lobe_f, (float*)d_out);
}

// Round 6
// 139.179 us; speedup vs baseline: 5.6838x; 1.0732x over previous
//
#include <hip/hip_runtime.h>
#include <math.h>

// B=8, T=2048, D=128, NH=4, HD=32. BT=16384 rows.
// Round 6: attention with REGISTER-RESIDENT P via swapped-operand MFMA:
//   QK^T computed as mfma(K,Q) -> C[key][q]: each lane owns one q-row's
//   scores; softmax is lane-local (scalar m, rs). V^T key-permutation kappa
//   chosen so the PV B-fragment is the lane's own cvt_pk words (no LDS P).
//   PV as mfma(V^T, P^T) -> C[d][q]. One barrier/tile, dbuf K/V staging.
// Scan: ends-only pass + carry + re-scan (impact stored bf16).

#define T_  2048

typedef short bf16x8 __attribute__((ext_vector_type(8)));
typedef float f32x4  __attribute__((ext_vector_type(4)));
typedef unsigned short ushort_t;

__device__ __forceinline__ float sigm(float x) { return 1.0f / (1.0f + __expf(-x)); }

__device__ __forceinline__ unsigned short f2bf(float x) {
    union { float f; unsigned u; } v; v.f = x;
    unsigned r = v.u + 0x7FFFu + ((v.u >> 16) & 1u);  // RNE
    return (unsigned short)(r >> 16);
}
__device__ __forceinline__ float bf2f(ushort_t u) {
    union { unsigned u; float f; } v; v.u = ((unsigned)u) << 16; return v.f;
}

// gelu(x) ~= x * sigmoid(1.595769f*(x+0.044715x^3)) in exp2 domain, 1 rcp.
__device__ __forceinline__ float gelu_f(float x) {
    const float e = exp2f(fmaf(0.044715f * x, x * x, x) * -2.3022083f);
    return x * __builtin_amdgcn_rcpf(1.0f + e);
}
// tanh(y) = 1 - 2/(exp2(y*2*log2e)+1)
__device__ __forceinline__ float tanh_f(float y) {
    const float e = exp2f(y * 2.8853900818f);
    return 1.0f - 2.0f * __builtin_amdgcn_rcpf(e + 1.0f);
}

// ---------------- prep: f32 -> bf16 for inputs + all weights -----------------
__global__ __launch_bounds__(256) void prep_kernel(
    const float* __restrict__ lob, const float* __restrict__ trade,
    const float* __restrict__ eiw, const float* __restrict__ ipw,
    const float* __restrict__ opw, const float* __restrict__ lobw,
    const float* __restrict__ trw, const float* __restrict__ ofw,
    ushort_t* __restrict__ pool)
{
    const size_t i8 = ((size_t)blockIdx.x * 256 + threadIdx.x) * 8;
    const float* src; size_t off;
    if      (i8 < 2097152) { src = lob;   off = 0; }
    else if (i8 < 4194304) { src = trade; off = 2097152; }
    else if (i8 < 4210688) { src = eiw;   off = 4194304; }
    else if (i8 < 4259840) { src = ipw;   off = 4210688; }
    else if (i8 < 4276224) { src = opw;   off = 4259840; }
    else if (i8 < 4308992) { src = lobw;  off = 4276224; }
    else if (i8 < 4341760) { src = trw;   off = 4308992; }
    else                   { src = ofw;   off = 4341760; }
    const float4 a = *(const float4*)(src + (i8 - off));
    const float4 b = *(const float4*)(src + (i8 - off) + 4);
    bf16x8 o;
    o[0] = (short)f2bf(a.x); o[1] = (short)f2bf(a.y);
    o[2] = (short)f2bf(a.z); o[3] = (short)f2bf(a.w);
    o[4] = (short)f2bf(b.x); o[5] = (short)f2bf(b.y);
    o[6] = (short)f2bf(b.z); o[7] = (short)f2bf(b.w);
    *(bf16x8*)(pool + i8) = o;
}

// ---------------- ei GEMM + LN + tanh*extra -> bf16 impact -------------------
__global__ __launch_bounds__(256) void gemm_ei(
    const ushort_t* __restrict__ Xb0, const ushort_t* __restrict__ Wb,
    const float* __restrict__ bias, const float* __restrict__ gamma,
    const float* __restrict__ beta, const float* __restrict__ extra,
    ushort_t* __restrict__ outb)
{
    __shared__ float red[32][2][2];
    const int tid = threadIdx.x, wid = tid >> 6, lane = tid & 63;
    const int c2 = lane & 15, g = lane >> 4;
    const int rowblk = wid >> 1, chf = wid & 1, cb0 = chf * 4;
    const int R0 = blockIdx.x * 32 + rowblk * 16;

    f32x4 acc[4] = {};
#pragma unroll
    for (int ch = 0; ch < 4; ch++) {
        const bf16x8 a = *(const bf16x8*)(Xb0 + (size_t)(R0 + c2) * 128 + ch * 32 + g * 8);
#pragma unroll
        for (int j = 0; j < 4; j++) {
            const bf16x8 b = *(const bf16x8*)(Wb + (size_t)((cb0 + j) * 16 + c2) * 128 + ch * 32 + g * 8);
            acc[j] = __builtin_amdgcn_mfma_f32_16x16x32_bf16(a, b, acc[j], 0, 0, 0);
        }
    }
    float gm[4], bt[4];
#pragma unroll
    for (int j = 0; j < 4; j++) {
        const int col = (cb0 + j) * 16 + c2;
        const float bb = bias[col];
        gm[j] = gamma[col]; bt[j] = beta[col];
#pragma unroll
        for (int r = 0; r < 4; r++) acc[j][r] += bb;
    }
#pragma unroll
    for (int r = 0; r < 4; r++) {
        float s = 0.f, ss = 0.f;
#pragma unroll
        for (int j = 0; j < 4; j++) { const float v = acc[j][r]; s += v; ss = fmaf(v, v, ss); }
#pragma unroll
        for (int o = 8; o; o >>= 1) { s += __shfl_xor(s, o); ss += __shfl_xor(ss, o); }
        if (c2 == 0) {
            red[rowblk * 16 + 4 * g + r][chf][0] = s;
            red[rowblk * 16 + 4 * g + r][chf][1] = ss;
        }
    }
    __syncthreads();
#pragma unroll
    for (int r = 0; r < 4; r++) {
        const int lr = rowblk * 16 + 4 * g + r;
        const float S  = red[lr][0][0] + red[lr][1][0];
        const float SS = red[lr][0][1] + red[lr][1][1];
        const float mean = S * (1.0f / 128.0f);
        float var = SS * (1.0f / 128.0f) - mean * mean;
        var = fmaxf(var, 0.0f);
        const float rstd = rsqrtf(var + 1e-5f);
        const int R = blockIdx.x * 32 + lr;
        const float ext = extra[R];
#pragma unroll
        for (int j = 0; j < 4; j++) {
            const float y = (acc[j][r] - mean) * rstd * gm[j] + bt[j];
            outb[(size_t)R * 128 + (cb0 + j) * 16 + c2] = f2bf(tanh_f(y) * ext);
        }
    }
}

// ---------------- fused enh (lobe+tre) + qkv ---------------------------------
__global__ __launch_bounds__(256) void enh_qkv(
    const ushort_t* __restrict__ lobb, const ushort_t* __restrict__ trab,
    const ushort_t* __restrict__ stab,
    const ushort_t* __restrict__ lobw, const ushort_t* __restrict__ trw,
    const ushort_t* __restrict__ ipw, const float* __restrict__ ipb,
    const float* __restrict__ lob_b, const float* __restrict__ lob_g,
    const float* __restrict__ lob_beta,
    const float* __restrict__ tr_b, const float* __restrict__ tr_g,
    const float* __restrict__ tr_beta,
    float* __restrict__ lobe_f, ushort_t* __restrict__ tre_bf,
    ushort_t* __restrict__ qo, ushort_t* __restrict__ ko, ushort_t* __restrict__ vo)
{
    __shared__ ushort_t lob_t[32][136];
    __shared__ ushort_t tre_t[32][136];
    __shared__ ushort_t vls[128][36];
    __shared__ float red[32][2][4];
    const int tid = threadIdx.x, wid = tid >> 6, lane = tid & 63;
    const int c2 = lane & 15, g = lane >> 4;
    const int rowblk = wid >> 1, chf = wid & 1, cb0 = chf * 4;
    const int RB = blockIdx.x * 32;
    const int R0 = RB + rowblk * 16;

    // ---- phase A: lobe & tre enh GEMMs (K=256) ----
    f32x4 aL[4] = {}, aT[4] = {};
#pragma unroll
    for (int ch = 0; ch < 8; ch++) {
        const int kk = (ch & 3) * 32;
        bf16x8 xl, xt;
        if (ch < 4) {
            xl = *(const bf16x8*)(lobb + (size_t)(R0 + c2) * 128 + kk + g * 8);
            xt = *(const bf16x8*)(trab + (size_t)(R0 + c2) * 128 + kk + g * 8);
        } else {
            xl = *(const bf16x8*)(stab + (size_t)(R0 + c2) * 128 + kk + g * 8);
            xt = xl;
        }
#pragma unroll
        for (int j = 0; j < 4; j++) {
            const size_t wo = (size_t)((cb0 + j) * 16 + c2) * 256 + ch * 32 + g * 8;
            aL[j] = __builtin_amdgcn_mfma_f32_16x16x32_bf16(xl, *(const bf16x8*)(lobw + wo), aL[j], 0, 0, 0);
            aT[j] = __builtin_amdgcn_mfma_f32_16x16x32_bf16(xt, *(const bf16x8*)(trw + wo), aT[j], 0, 0, 0);
        }
    }
#pragma unroll
    for (int j = 0; j < 4; j++) {
        const int col = (cb0 + j) * 16 + c2;
        const float bL = lob_b[col], bT = tr_b[col];
#pragma unroll
        for (int r = 0; r < 4; r++) { aL[j][r] += bL; aT[j][r] += bT; }
    }
#pragma unroll
    for (int r = 0; r < 4; r++) {
        float sL = 0.f, ssL = 0.f, sT = 0.f, ssT = 0.f;
#pragma unroll
        for (int j = 0; j < 4; j++) {
            const float vL = aL[j][r], vT = aT[j][r];
            sL += vL; ssL = fmaf(vL, vL, ssL);
            sT += vT; ssT = fmaf(vT, vT, ssT);
        }
#pragma unroll
        for (int o = 8; o; o >>= 1) {
            sL += __shfl_xor(sL, o); ssL += __shfl_xor(ssL, o);
            sT += __shfl_xor(sT, o); ssT += __shfl_xor(ssT, o);
        }
        if (c2 == 0) {
            float* rd = red[rowblk * 16 + 4 * g + r][chf];
            rd[0] = sL; rd[1] = ssL; rd[2] = sT; rd[3] = ssT;
        }
    }
    __syncthreads();
#pragma unroll
    for (int r = 0; r < 4; r++) {
        const int lr = rowblk * 16 + 4 * g + r;
        const int R = RB + lr;
        const float SL  = red[lr][0][0] + red[lr][1][0];
        const float SSL = red[lr][0][1] + red[lr][1][1];
        const float ST  = red[lr][0][2] + red[lr][1][2];
        const float SST = red[lr][0][3] + red[lr][1][3];
        const float mL = SL * (1.0f / 128.0f), mT = ST * (1.0f / 128.0f);
        const float rL = rsqrtf(fmaxf(SSL * (1.0f / 128.0f) - mL * mL, 0.0f) + 1e-5f);
        const float rT = rsqrtf(fmaxf(SST * (1.0f / 128.0f) - mT * mT, 0.0f) + 1e-5f);
#pragma unroll
        for (int j = 0; j < 4; j++) {
            const int col = (cb0 + j) * 16 + c2;
            const float yL = gelu_f((aL[j][r] - mL) * rL * lob_g[col] + lob_beta[col]);
            const float yT = gelu_f((aT[j][r] - mT) * rT * tr_g[col] + tr_beta[col]);
            lobe_f[(size_t)R * 128 + col] = yL;
            lob_t[lr][col] = f2bf(yL);
            const ushort_t tb = f2bf(yT);
            tre_bf[(size_t)R * 128 + col] = tb;
            tre_t[lr][col] = tb;
        }
    }
    __syncthreads();

    // ---- phase B: q from lob_t, k/v from tre_t ----
    const float qscale = 0.17677669529663687f * 1.4426950408889634f;
#pragma unroll
    for (int which = 0; which < 3; which++) {
        const ushort_t (*src)[136] = (which == 0) ? lob_t : tre_t;
        const ushort_t* Wp = ipw + (size_t)which * 16384;
        f32x4 pa[4] = {};
#pragma unroll
        for (int ch = 0; ch < 4; ch++) {
            const bf16x8 a = *(const bf16x8*)&src[rowblk * 16 + c2][ch * 32 + g * 8];
#pragma unroll
            for (int j = 0; j < 4; j++) {
                const bf16x8 b = *(const bf16x8*)(Wp + (size_t)((cb0 + j) * 16 + c2) * 128 + ch * 32 + g * 8);
                pa[j] = __builtin_amdgcn_mfma_f32_16x16x32_bf16(a, b, pa[j], 0, 0, 0);
            }
        }
        if (which < 2) {
            ushort_t* dst = (which == 0) ? qo : ko;
            const float sc = (which == 0) ? qscale : 1.0f;
#pragma unroll
            for (int j = 0; j < 4; j++) {
                const int col = (cb0 + j) * 16 + c2;
                const float bb = ipb[which * 128 + col];
                const int h = col >> 5, hd = col & 31;
#pragma unroll
                for (int r = 0; r < 4; r++) {
                    const int R = R0 + 4 * g + r;
                    const int b = R >> 11, t = R & 2047;
                    dst[(((size_t)b * 4 + h) * 2048 + t) * 32 + hd] = f2bf((pa[j][r] + bb) * sc);
                }
            }
        } else {
#pragma unroll
            for (int j = 0; j < 4; j++) {
                const int col = (cb0 + j) * 16 + c2;
                const float bb = ipb[256 + col];
#pragma unroll
                for (int r = 0; r < 4; r++)
                    vls[col][rowblk * 16 + 4 * g + r] = f2bf(pa[j][r] + bb);
            }
        }
    }
    __syncthreads();
    // V^T global write with kappa permutation: position p (within 32-half)
    //   g2=p>>3, j2=p&7 -> local key = 4*g2 + j2 + (j2>=4 ? 12 : 0)
    {
        const int col = tid >> 1, hf = tid & 1;
        const int h = col >> 5, hd = col & 31;
        const int b = RB >> 11;
        unsigned w[8];
#pragma unroll
        for (int e = 0; e < 8; e++) {
            const int p0 = hf * 16 + 2 * e;
            const int g2 = p0 >> 3, j2 = p0 & 7;
            const int lk = 4 * g2 + j2 + (j2 >= 4 ? 12 : 0);
            w[e] = (unsigned)vls[col][lk] | ((unsigned)vls[col][lk + 1] << 16);
        }
        ushort_t* dst = vo + (((size_t)b * 4 + h) * 32 + hd) * 2048 + (RB & 2047) + hf * 16;
        *(uint4*)dst       = *(const uint4*)&w[0];
        *(uint4*)(dst + 8) = *(const uint4*)&w[4];
    }
}

// ---------------- flash attention: register-P, swapped-operand MFMA ----------
__global__ __launch_bounds__(256) void attn_kernel(
    const ushort_t* __restrict__ q, const ushort_t* __restrict__ k,
    const ushort_t* __restrict__ vtg, ushort_t* __restrict__ ctx)
{
    __shared__ ushort_t ks[2][64][40];   // K tile   [buf][key][hd]
    __shared__ ushort_t vt[2][32][72];   // V^T tile [buf][d][kappa-pos]
    const int tid = threadIdx.x, wid = tid >> 6, lane = tid & 63;
    const int c = lane & 15, g = lane >> 4;
    const int qt = blockIdx.x, bh = blockIdx.y, b = bh >> 2, h = bh & 3;
    const ushort_t* kb_ = k   + (size_t)bh * 65536;
    const ushort_t* vb_ = vtg + (size_t)bh * 65536;

    // Q fragment (B-operand role): q-row = wid*16 + c, hd = g*8..
    const bf16x8 qf = *(const bf16x8*)(q + ((size_t)bh * 2048 + qt * 64 + wid * 16 + c) * 32 + g * 8);

    float m_i = 8.0f, rs = 0.0f;     // lane-local: this lane's q-row
    f32x4 acc[2] = {};               // C[d][q]: acc[nb][r] = ctx[d=nb*16+4g+r][q=c]

    const int srow = tid >> 2, ssg = tid & 3;  // K staging
    const int vd = tid >> 3, vkg = tid & 7;    // V^T staging

    {
        const bf16x8 kk8 = *(const bf16x8*)(kb_ + (size_t)srow * 32 + ssg * 8);
        const bf16x8 vv8 = *(const bf16x8*)(vb_ + (size_t)vd * 2048 + vkg * 8);
        *(bf16x8*)&ks[0][srow][ssg * 8] = kk8;
        *(bf16x8*)&vt[0][vd][vkg * 8] = vv8;
    }
    __syncthreads();

    for (int kt = 0; kt < 32; kt++) {
        const int cur = kt & 1;
        bf16x8 kk8, vv8;
        if (kt + 1 < 32) {
            kk8 = *(const bf16x8*)(kb_ + ((size_t)(kt + 1) * 64 + srow) * 32 + ssg * 8);
            vv8 = *(const bf16x8*)(vb_ + (size_t)vd * 2048 + (kt + 1) * 64 + vkg * 8);
        }

        // ---- QK^T swapped: s[kb2] = mfma(A=K, B=Q) -> C[key][q]
        // lane (c,g) reg r: score(q=c, key=kb2*16+4g+r)
        f32x4 s[4];
        __builtin_amdgcn_s_setprio(1);
#pragma unroll
        for (int kb2 = 0; kb2 < 4; kb2++) {
            const bf16x8 kf = *(const bf16x8*)&ks[cur][kb2 * 16 + c][g * 8];
            f32x4 z = {};
            s[kb2] = __builtin_amdgcn_mfma_f32_16x16x32_bf16(kf, qf, z, 0, 0, 0);
        }
        __builtin_amdgcn_s_setprio(0);

        // ---- overflow guard (rare path) ----
        float lm = s[0][0];
#pragma unroll
        for (int kb2 = 0; kb2 < 4; kb2++)
#pragma unroll
            for (int r = 0; r < 4; r++) lm = fmaxf(lm, s[kb2][r]);
        if (__any(lm > m_i + 40.0f)) {
            float tm = lm;
            tm = fmaxf(tm, __shfl_xor(tm, 16));
            tm = fmaxf(tm, __shfl_xor(tm, 32));
            const float mn = fmaxf(m_i, tm);
            const float al = exp2f(m_i - mn);
            rs *= al;
#pragma unroll
            for (int nb = 0; nb < 2; nb++)
#pragma unroll
                for (int r = 0; r < 4; r++) acc[nb][r] *= al;
            m_i = mn;
        }

        // ---- p = exp2(s - m), all lane-local; pack to bf16 words ----
#pragma unroll
        for (int kb2 = 0; kb2 < 4; kb2++)
#pragma unroll
            for (int r = 0; r < 4; r++) s[kb2][r] = exp2f(s[kb2][r] - m_i);
        rs += ((s[0][0] + s[0][1]) + (s[0][2] + s[0][3]))
            + ((s[1][0] + s[1][1]) + (s[1][2] + s[1][3]))
            + ((s[2][0] + s[2][1]) + (s[2][2] + s[2][3]))
            + ((s[3][0] + s[3][1]) + (s[3][2] + s[3][3]));
        union { unsigned u[4]; bf16x8 v; } pf0, pf1;
        asm("v_cvt_pk_bf16_f32 %0, %1, %2" : "=v"(pf0.u[0]) : "v"(s[0][0]), "v"(s[0][1]));
        asm("v_cvt_pk_bf16_f32 %0, %1, %2" : "=v"(pf0.u[1]) : "v"(s[0][2]), "v"(s[0][3]));
        asm("v_cvt_pk_bf16_f32 %0, %1, %2" : "=v"(pf0.u[2]) : "v"(s[1][0]), "v"(s[1][1]));
        asm("v_cvt_pk_bf16_f32 %0, %1, %2" : "=v"(pf0.u[3]) : "v"(s[1][2]), "v"(s[1][3]));
        asm("v_cvt_pk_bf16_f32 %0, %1, %2" : "=v"(pf1.u[0]) : "v"(s[2][0]), "v"(s[2][1]));
        asm("v_cvt_pk_bf16_f32 %0, %1, %2" : "=v"(pf1.u[1]) : "v"(s[2][2]), "v"(s[2][3]));
        asm("v_cvt_pk_bf16_f32 %0, %1, %2" : "=v"(pf1.u[2]) : "v"(s[3][0]), "v"(s[3][1]));
        asm("v_cvt_pk_bf16_f32 %0, %1, %2" : "=v"(pf1.u[3]) : "v"(s[3][2]), "v"(s[3][3]));

        // ---- PV swapped: acc[nb] += mfma(A=V^T frag, B=P^T frag) ----
        __builtin_amdgcn_s_setprio(1);
#pragma unroll
        for (int nb = 0; nb < 2; nb++) {
            const bf16x8 v0 = *(const bf16x8*)&vt[cur][nb * 16 + c][g * 8];
            const bf16x8 v1 = *(const bf16x8*)&vt[cur][nb * 16 + c][32 + g * 8];
            acc[nb] = __builtin_amdgcn_mfma_f32_16x16x32_bf16(v0, pf0.v, acc[nb], 0, 0, 0);
            acc[nb] = __builtin_amdgcn_mfma_f32_16x16x32_bf16(v1, pf1.v, acc[nb], 0, 0, 0);
        }
        __builtin_amdgcn_s_setprio(0);

        if (kt + 1 < 32) {
            *(bf16x8*)&ks[cur ^ 1][srow][ssg * 8] = kk8;
            *(bf16x8*)&vt[cur ^ 1][vd][vkg * 8] = vv8;
        }
        __syncthreads();
    }

    // ---- epilogue: reduce rs over the 4 g-lanes of this q, pack & store ----
    rs += __shfl_xor(rs, 16);
    rs += __shfl_xor(rs, 32);
    const float inv = __builtin_amdgcn_rcpf(rs);
    const int q_ = qt * 64 + wid * 16 + c;
    ushort_t* dst = ctx + ((size_t)(b * 2048 + q_)) * 128 + h * 32;
#pragma unroll
    for (int nb = 0; nb < 2; nb++) {
        unsigned w0, w1;
        const float a0 = acc[nb][0] * inv, a1 = acc[nb][1] * inv;
        const float a2 = acc[nb][2] * inv, a3 = acc[nb][3] * inv;
        asm("v_cvt_pk_bf16_f32 %0, %1, %2" : "=v"(w0) : "v"(a0), "v"(a1));
        asm("v_cvt_pk_bf16_f32 %0, %1, %2" : "=v"(w1) : "v"(a2), "v"(a3));
        uint2 wv; wv.x = w0; wv.y = w1;
        *(uint2*)(dst + nb * 16 + 4 * g) = wv;
    }
}

// ---------------- fused out-proj + residual-LN + final GEMM ------------------
__global__ __launch_bounds__(256) void out_fuse(
    const ushort_t* __restrict__ ctxb, const ushort_t* __restrict__ treb,
    const ushort_t* __restrict__ opw, const float* __restrict__ opb,
    const float* __restrict__ cn_g, const float* __restrict__ cn_b,
    const ushort_t* __restrict__ ofw, const float* __restrict__ of_b,
    const float* __restrict__ of_g, const float* __restrict__ of_beta,
    const float* __restrict__ lobe_f, float* __restrict__ out)
{
    __shared__ ushort_t fus_t[32][136];
    __shared__ float red[32][2][2];
    const int tid = threadIdx.x, wid = tid >> 6, lane = tid & 63;
    const int c2 = lane & 15, g = lane >> 4;
    const int rowblk = wid >> 1, chf = wid & 1, cb0 = chf * 4;
    const int RB = blockIdx.x * 32;
    const int R0 = RB + rowblk * 16;

    f32x4 acc[4] = {};
#pragma unroll
    for (int ch = 0; ch < 4; ch++) {
        const bf16x8 a = *(const bf16x8*)(ctxb + (size_t)(R0 + c2) * 128 + ch * 32 + g * 8);
#pragma unroll
        for (int j = 0; j < 4; j++) {
            const bf16x8 b = *(const bf16x8*)(opw + (size_t)((cb0 + j) * 16 + c2) * 128 + ch * 32 + g * 8);
            acc[j] = __builtin_amdgcn_mfma_f32_16x16x32_bf16(a, b, acc[j], 0, 0, 0);
        }
    }
#pragma unroll
    for (int j = 0; j < 4; j++) {
        const int col = (cb0 + j) * 16 + c2;
        const float bb = opb[col];
#pragma unroll
        for (int r = 0; r < 4; r++)
            acc[j][r] += bb + lobe_f[(size_t)(R0 + 4 * g + r) * 128 + col];
    }
#pragma unroll
    for (int r = 0; r < 4; r++) {
        float s = 0.f, ss = 0.f;
#pragma unroll
        for (int j = 0; j < 4; j++) { const float v = acc[j][r]; s += v; ss = fmaf(v, v, ss); }
#pragma unroll
        for (int o = 8; o; o >>= 1) { s += __shfl_xor(s, o); ss += __shfl_xor(ss, o); }
        if (c2 == 0) {
            red[rowblk * 16 + 4 * g + r][chf][0] = s;
            red[rowblk * 16 + 4 * g + r][chf][1] = ss;
        }
    }
    __syncthreads();
#pragma unroll
    for (int r = 0; r < 4; r++) {
        const int lr = rowblk * 16 + 4 * g + r;
        const float S  = red[lr][0][0] + red[lr][1][0];
        const float SS = red[lr][0][1] + red[lr][1][1];
        const float mean = S * (1.0f / 128.0f);
        const float rstd = rsqrtf(fmaxf(SS * (1.0f / 128.0f) - mean * mean, 0.0f) + 1e-5f);
#pragma unroll
        for (int j = 0; j < 4; j++) {
            const int col = (cb0 + j) * 16 + c2;
            fus_t[lr][col] = f2bf((acc[j][r] - mean) * rstd * cn_g[col] + cn_b[col]);
        }
    }
    __syncthreads();

    f32x4 a2[4] = {};
#pragma unroll
    for (int ch = 0; ch < 8; ch++) {
        bf16x8 a;
        if (ch < 4) a = *(const bf16x8*)&fus_t[rowblk * 16 + c2][ch * 32 + g * 8];
        else        a = *(const bf16x8*)(treb + (size_t)(R0 + c2) * 128 + (ch - 4) * 32 + g * 8);
#pragma unroll
        for (int j = 0; j < 4; j++) {
            const bf16x8 b = *(const bf16x8*)(ofw + (size_t)((cb0 + j) * 16 + c2) * 256 + ch * 32 + g * 8);
            a2[j] = __builtin_amdgcn_mfma_f32_16x16x32_bf16(a, b, a2[j], 0, 0, 0);
        }
    }
#pragma unroll
    for (int j = 0; j < 4; j++) {
        const float bb = of_b[(cb0 + j) * 16 + c2];
#pragma unroll
        for (int r = 0; r < 4; r++) a2[j][r] += bb;
    }
#pragma unroll
    for (int r = 0; r < 4; r++) {
        float s = 0.f, ss = 0.f;
#pragma unroll
        for (int j = 0; j < 4; j++) { const float v = a2[j][r]; s += v; ss = fmaf(v, v, ss); }
#pragma unroll
        for (int o = 8; o; o >>= 1) { s += __shfl_xor(s, o); ss += __shfl_xor(ss, o); }
        if (c2 == 0) {
            red[rowblk * 16 + 4 * g + r][chf][0] = s;
            red[rowblk * 16 + 4 * g + r][chf][1] = ss;
        }
    }
    __syncthreads();
#pragma unroll
    for (int r = 0; r < 4; r++) {
        const int lr = rowblk * 16 + 4 * g + r;
        const float S  = red[lr][0][0] + red[lr][1][0];
        const float SS = red[lr][0][1] + red[lr][1][1];
        const float mean = S * (1.0f / 128.0f);
        const float rstd = rsqrtf(fmaxf(SS * (1.0f / 128.0f) - mean * mean, 0.0f) + 1e-5f);
        const int R = RB + lr;
#pragma unroll
        for (int j = 0; j < 4; j++) {
            const int col = (cb0 + j) * 16 + c2;
            const float y = (a2[j][r] - mean) * rstd * of_g[col] + of_beta[col];
            out[(size_t)R * 128 + col] = gelu_f(y);
        }
    }
}

// ---------------- decay scan: ends -> carry -> re-scan -----------------------
__global__ void scan_ends_kernel(const ushort_t* __restrict__ imp,
                                 const float* __restrict__ decay,
                                 float* __restrict__ ends)
{
    const int c = threadIdx.x;
    const int ch = blockIdx.x, b = blockIdx.y;
    const float d = sigm(decay[c]);
    const size_t base = ((size_t)b * T_ + ch * 64) * 128 + c;
    float s = 0.0f;
#pragma unroll 4
    for (int tl = 0; tl < 64; tl++)
        s = fmaf(d, s, bf2f(imp[base + (size_t)tl * 128]));
    ends[((size_t)b * 32 + ch) * 128 + c] = s;
}

__global__ void scan_carry_kernel(const float* __restrict__ ends,
                                  const float* __restrict__ decay,
                                  float* __restrict__ carry)
{
    const int c = threadIdx.x;
    const int b = blockIdx.x;
    const float d = sigm(decay[c]);
    float dl = d;
#pragma unroll
    for (int i = 0; i < 6; i++) dl *= dl;  // d^64
    float e = 0.0f;
#pragma unroll
    for (int ch = 0; ch < 32; ch++) {
        carry[((size_t)b * 32 + ch) * 128 + c] = e;
        e = fmaf(dl, e, ends[((size_t)b * 32 + ch) * 128 + c]);
    }
}

__global__ void scan_fin_kernel(const ushort_t* __restrict__ imp,
                                const float* __restrict__ decay,
                                const float* __restrict__ carry,
                                ushort_t* __restrict__ stbf)
{
    const int c = threadIdx.x;
    const int ch = blockIdx.x, b = blockIdx.y;
    const float d = sigm(decay[c]);
    float s = carry[((size_t)b * 32 + ch) * 128 + c];
    const size_t base = ((size_t)b * T_ + ch * 64) * 128 + c;
#pragma unroll 4
    for (int tl = 0; tl < 64; tl++) {
        s = fmaf(d, s, bf2f(imp[base + (size_t)tl * 128]));
        stbf[base + (size_t)tl * 128] = f2bf(s);
    }
}

extern "C" void kernel_launch(void* const* d_in, const int* in_sizes, int n_in,
                              void* d_out, int out_size, void* d_ws, size_t ws_size,
                              hipStream_t stream)
{
    const float* lob_feat   = (const float*)d_in[0];
    const float* trade_feat = (const float*)d_in[1];
    const float* has_trade  = (const float*)d_in[2];
    const float* ei_w       = (const float*)d_in[3];
    const float* ei_b       = (const float*)d_in[4];
    const float* ei_g       = (const float*)d_in[5];
    const float* ei_beta    = (const float*)d_in[6];
    const float* decay      = (const float*)d_in[7];
    const float* in_proj_w  = (const float*)d_in[8];
    const float* in_proj_b  = (const float*)d_in[9];
    const float* out_proj_w = (const float*)d_in[10];
    const float* out_proj_b = (const float*)d_in[11];
    const float* cn_g       = (const float*)d_in[12];
    const float* cn_b       = (const float*)d_in[13];
    const float* lob_w      = (const float*)d_in[14];
    const float* lob_b      = (const float*)d_in[15];
    const float* lob_g      = (const float*)d_in[16];
    const float* lob_beta   = (const float*)d_in[17];
    const float* tr_w       = (const float*)d_in[18];
    const float* tr_b       = (const float*)d_in[19];
    const float* tr_g       = (const float*)d_in[20];
    const float* tr_beta    = (const float*)d_in[21];
    const float* of_w       = (const float*)d_in[22];
    const float* of_b       = (const float*)d_in[23];
    const float* of_g       = (const float*)d_in[24];
    const float* of_beta    = (const float*)d_in[25];

    char* W = (char*)d_ws;
    const size_t MB = 1u << 20;
    float*    lobe_f   = (float*)W;                  // 8 MB
    float*    carry    = (float*)(W + 8 * MB);       // 128 KB
    float*    ends     = (float*)(W + 8 * MB + 256 * 1024);
    ushort_t* pool     = (ushort_t*)(W + 9 * MB);    // 8.75 MB
    ushort_t* imp_bf   = (ushort_t*)(W + 18 * MB);   // 4 MB
    ushort_t* state_bf = (ushort_t*)(W + 22 * MB);
    ushort_t* tre_bf   = (ushort_t*)(W + 26 * MB);
    ushort_t* q_bf     = (ushort_t*)(W + 30 * MB);
    ushort_t* k_bf     = (ushort_t*)(W + 34 * MB);
    ushort_t* vt_g     = (ushort_t*)(W + 38 * MB);
    ushort_t* ctx_bf   = (ushort_t*)(W + 42 * MB);

    ushort_t* lob_bf   = pool;
    ushort_t* trade_bf = pool + 2097152;
    ushort_t* eiw_bf   = pool + 4194304;
    ushort_t* ipw_bf   = pool + 4210688;
    ushort_t* opw_bf   = pool + 4259840;
    ushort_t* lobw_bf  = pool + 4276224;
    ushort_t* trw_bf   = pool + 4308992;
    ushort_t* ofw_bf   = pool + 4341760;

    const dim3 blk(256);

    prep_kernel<<<dim3(2136), blk, 0, stream>>>(lob_feat, trade_feat, ei_w, in_proj_w,
                                                out_proj_w, lob_w, tr_w, of_w, pool);
    // 1. impact -> imp_bf (bf16)
    gemm_ei<<<dim3(512), blk, 0, stream>>>(trade_bf, eiw_bf, ei_b, ei_g, ei_beta,
                                           has_trade, imp_bf);
    // 2. scan: ends -> carry -> full re-scan -> state_bf
    scan_ends_kernel<<<dim3(32, 8), dim3(128), 0, stream>>>(imp_bf, decay, ends);
    scan_carry_kernel<<<dim3(8), dim3(128), 0, stream>>>(ends, decay, carry);
    scan_fin_kernel<<<dim3(32, 8), dim3(128), 0, stream>>>(imp_bf, decay, carry, state_bf);
    // 3. lob_enh + trade_enh + qkv (fused)
    enh_qkv<<<dim3(512), blk, 0, stream>>>(lob_bf, trade_bf, state_bf, lobw_bf, trw_bf,
                                           ipw_bf, in_proj_b, lob_b, lob_g, lob_beta,
                                           tr_b, tr_g, tr_beta, lobe_f, tre_bf,
                                           q_bf, k_bf, vt_g);
    // 4. attention
    attn_kernel<<<dim3(32, 32), blk, 0, stream>>>(q_bf, k_bf, vt_g, ctx_bf);
    // 5. out-proj + residual LN + final GEMM (fused)
    out_fuse<<<dim3(512), blk, 0, stream>>>(ctx_bf, tre_bf, opw_bf, out_proj_b, cn_g, cn_b,
                                            ofw_bf, of_b, of_g, of_beta, lobe_f, (float*)d_out);
}